// Round 3
// baseline (926.550 us; speedup 1.0000x reference)
//
#include <hip/hip_runtime.h>
#include <hip/hip_bf16.h>

// ---------- constants ----------
constexpr int Bb   = 8;
constexpr int Hh   = 96;
constexpr int Ww   = 96;
constexpr int Cc   = 192;
constexpr int WS   = 12;
constexpr int WS2  = 144;            // 12*12
constexpr int HEADS= 8;
constexpr int HD   = 24;
constexpr int NWIN = Bb * (Hh/WS) * (Ww/WS);   // 512
constexpr int Mrows= NWIN * WS2;               // 73728
constexpr int QKVN = 3 * Cc;                   // 576

__device__ __forceinline__ float us2f(unsigned short u) {
    unsigned int i = ((unsigned int)u) << 16;
    float f; __builtin_memcpy(&f, &i, 4);
    return f;
}
__device__ __forceinline__ unsigned short f2us(float f) {
    unsigned int i; __builtin_memcpy(&i, &f, 4);
    unsigned int lsb = (i >> 16) & 1u;
    i += 0x7fffu + lsb;
    return (unsigned short)(i >> 16);
}

// ---------------------------------------------------------------
// Kernel 1: qkv = window_partition(x) @ qkv_w^T + qkv_b
// x is f32; output bf16 [Mrows][576].
// tiles: 64(M) x 64(N), K-tile 16, block 16x16, 4x4 per thread.
// ---------------------------------------------------------------
__global__ __launch_bounds__(256) void qkv_gemm(
        const float* __restrict__ x,      // f32 [B*N*C]
        const float* __restrict__ w,      // f32 [576][192]
        const float* __restrict__ bias,   // f32 [576]
        unsigned short* __restrict__ qkv) // bf16 [Mrows][576]
{
    __shared__ float As[64][17];
    __shared__ float Bs[64][17];

    const int bm = blockIdx.x;          // 0..1151
    const int bn = blockIdx.y;          // 0..8
    const int tx = threadIdx.x, ty = threadIdx.y;
    const int tid = ty * 16 + tx;
    const int m0 = bm * 64, n0 = bn * 64;

    const int arow = tid >> 2;          // 0..63
    const int ak   = (tid & 3) * 4;     // 0,4,8,12

    // window gather for A row (m0 + arow)
    const int m    = m0 + arow;
    const int widx = m / WS2;
    const int pos  = m % WS2;
    const int b    = widx >> 6;
    const int wi   = (widx >> 3) & 7;
    const int wj   = widx & 7;
    const int r    = pos / WS;
    const int s    = pos % WS;
    const long xrow = ((long)((b * Hh + wi * WS + r) * Ww + wj * WS + s)) * Cc;

    const long brow = (long)(n0 + arow) * Cc;

    float acc[4][4] = {};

    for (int k0 = 0; k0 < Cc; k0 += 16) {
        float4 av = *reinterpret_cast<const float4*>(x + xrow + k0 + ak);
        As[arow][ak + 0] = av.x;
        As[arow][ak + 1] = av.y;
        As[arow][ak + 2] = av.z;
        As[arow][ak + 3] = av.w;
        float4 bv = *reinterpret_cast<const float4*>(w + brow + k0 + ak);
        Bs[arow][ak + 0] = bv.x;
        Bs[arow][ak + 1] = bv.y;
        Bs[arow][ak + 2] = bv.z;
        Bs[arow][ak + 3] = bv.w;
        __syncthreads();
        #pragma unroll
        for (int k = 0; k < 16; ++k) {
            float a0 = As[ty*4+0][k], a1 = As[ty*4+1][k], a2 = As[ty*4+2][k], a3 = As[ty*4+3][k];
            float b0 = Bs[tx*4+0][k], b1 = Bs[tx*4+1][k], b2 = Bs[tx*4+2][k], b3 = Bs[tx*4+3][k];
            acc[0][0] += a0*b0; acc[0][1] += a0*b1; acc[0][2] += a0*b2; acc[0][3] += a0*b3;
            acc[1][0] += a1*b0; acc[1][1] += a1*b1; acc[1][2] += a1*b2; acc[1][3] += a1*b3;
            acc[2][0] += a2*b0; acc[2][1] += a2*b1; acc[2][2] += a2*b2; acc[2][3] += a2*b3;
            acc[3][0] += a3*b0; acc[3][1] += a3*b1; acc[3][2] += a3*b2; acc[3][3] += a3*b3;
        }
        __syncthreads();
    }

    #pragma unroll
    for (int i = 0; i < 4; ++i) {
        const long orow = (long)(m0 + ty*4 + i) * QKVN;
        #pragma unroll
        for (int j = 0; j < 4; ++j) {
            const int n = n0 + tx*4 + j;
            qkv[orow + n] = f2us(acc[i][j] + bias[n]);
        }
    }
}

// ---------------------------------------------------------------
// Kernel 2: per-(window, head) attention with online softmax.
// block = 192 threads; threads 0..143 each own one query row.
// ---------------------------------------------------------------
__global__ __launch_bounds__(192) void attn_kernel(
        const unsigned short* __restrict__ qkv,    // bf16 [Mrows][576]
        const float* __restrict__ btab,            // f32 [529][8]
        unsigned short* __restrict__ aout)         // bf16 [Mrows][192]
{
    __shared__ float Ks[WS2][HD];
    __shared__ float Vs[WS2][HD];
    __shared__ float Bh[529];

    const int blk  = blockIdx.x;     // 0..4095
    const int win  = blk >> 3;
    const int head = blk & 7;
    const int tid  = threadIdx.x;

    const long base = (long)win * WS2 * QKVN;
    const int hoff = head * HD;

    for (int e = tid; e < WS2 * HD; e += 192) {
        const int p = e / HD, d = e % HD;
        Ks[p][d] = us2f(qkv[base + (long)p * QKVN + Cc     + hoff + d]);
        Vs[p][d] = us2f(qkv[base + (long)p * QKVN + 2*Cc   + hoff + d]);
    }
    for (int e = tid; e < 529; e += 192)
        Bh[e] = btab[e * HEADS + head];
    __syncthreads();

    if (tid < WS2) {
        const float scale = 0.2041241452319315f;   // 1/sqrt(24)
        float qf[HD];
        #pragma unroll
        for (int d = 0; d < HD; ++d)
            qf[d] = us2f(qkv[base + (long)tid * QKVN + hoff + d]) * scale;

        const int rq = tid / WS, sq = tid % WS;
        float mmax = -1e30f, l = 0.f;
        float out[HD];
        #pragma unroll
        for (int d = 0; d < HD; ++d) out[d] = 0.f;

        for (int j = 0; j < WS2; ++j) {
            float dot = 0.f;
            #pragma unroll
            for (int d = 0; d < HD; ++d) dot += qf[d] * Ks[j][d];
            const int rj = j / WS, sj = j % WS;
            dot += Bh[(rq - rj + 11) * 23 + (sq - sj + 11)];
            float p;
            if (dot > mmax) {
                const float c = __expf(mmax - dot);
                l *= c;
                #pragma unroll
                for (int d = 0; d < HD; ++d) out[d] *= c;
                mmax = dot;
                p = 1.f;
            } else {
                p = __expf(dot - mmax);
            }
            l += p;
            #pragma unroll
            for (int d = 0; d < HD; ++d) out[d] += p * Vs[j][d];
        }
        const float inv = 1.f / l;
        const long ob = (long)(win * WS2 + tid) * Cc + hoff;
        #pragma unroll
        for (int d = 0; d < HD; ++d)
            aout[ob + d] = f2us(out[d] * inv);
    }
}

// ---------------------------------------------------------------
// Kernel 3: out = window_reverse(attn_out @ proj_w^T + proj_b) + LPE
// Epilogue fuses window-reverse scatter + depthwise 3x3 conv + mask.
// Output is f32 (reference output dtype).
// ---------------------------------------------------------------
__global__ __launch_bounds__(256) void proj_lpe(
        const unsigned short* __restrict__ aout,   // bf16 [Mrows][192]
        const float* __restrict__ pw,              // f32 [192][192]
        const float* __restrict__ pb,              // f32 [192]
        const float* __restrict__ x,               // f32 [B*N*C]
        const float* __restrict__ lw,              // f32 [192][9]
        const float* __restrict__ lb,              // f32 [192]
        const float* __restrict__ lsc,             // f32 [1]
        const float* __restrict__ mask,            // f32 [B][H][W]
        float* __restrict__ out)                   // f32 [B*N*C]
{
    __shared__ float As[64][17];
    __shared__ float Bs[64][17];

    const int bm = blockIdx.x;          // 0..1151
    const int bn = blockIdx.y;          // 0..2
    const int tx = threadIdx.x, ty = threadIdx.y;
    const int tid = ty * 16 + tx;
    const int m0 = bm * 64, n0 = bn * 64;

    const int arow = tid >> 2;
    const int ak   = (tid & 3) * 4;
    const long arowg = (long)(m0 + arow) * Cc;
    const long browg = (long)(n0 + arow) * Cc;

    float acc[4][4] = {};

    for (int k0 = 0; k0 < Cc; k0 += 16) {
        ushort4 av = *reinterpret_cast<const ushort4*>(aout + arowg + k0 + ak);
        As[arow][ak + 0] = us2f(av.x);
        As[arow][ak + 1] = us2f(av.y);
        As[arow][ak + 2] = us2f(av.z);
        As[arow][ak + 3] = us2f(av.w);
        float4 bv = *reinterpret_cast<const float4*>(pw + browg + k0 + ak);
        Bs[arow][ak + 0] = bv.x;
        Bs[arow][ak + 1] = bv.y;
        Bs[arow][ak + 2] = bv.z;
        Bs[arow][ak + 3] = bv.w;
        __syncthreads();
        #pragma unroll
        for (int k = 0; k < 16; ++k) {
            float a0 = As[ty*4+0][k], a1 = As[ty*4+1][k], a2 = As[ty*4+2][k], a3 = As[ty*4+3][k];
            float b0 = Bs[tx*4+0][k], b1 = Bs[tx*4+1][k], b2 = Bs[tx*4+2][k], b3 = Bs[tx*4+3][k];
            acc[0][0] += a0*b0; acc[0][1] += a0*b1; acc[0][2] += a0*b2; acc[0][3] += a0*b3;
            acc[1][0] += a1*b0; acc[1][1] += a1*b1; acc[1][2] += a1*b2; acc[1][3] += a1*b3;
            acc[2][0] += a2*b0; acc[2][1] += a2*b1; acc[2][2] += a2*b2; acc[2][3] += a2*b3;
            acc[3][0] += a3*b0; acc[3][1] += a3*b1; acc[3][2] += a3*b2; acc[3][3] += a3*b3;
        }
        __syncthreads();
    }

    const float lscale = lsc[0];

    #pragma unroll
    for (int i = 0; i < 4; ++i) {
        const int m    = m0 + ty*4 + i;
        const int widx = m / WS2;
        const int pos  = m % WS2;
        const int b    = widx >> 6;
        const int wi   = (widx >> 3) & 7;
        const int wj   = widx & 7;
        const int h    = wi * WS + pos / WS;
        const int w_   = wj * WS + pos % WS;
        const float mv = mask[(b * Hh + h) * Ww + w_] * lscale;
        const long orow = ((long)(b * Hh + h) * Ww + w_) * Cc;

        #pragma unroll
        for (int j = 0; j < 4; ++j) {
            const int c = n0 + tx*4 + j;
            // depthwise 3x3 conv (cross-correlation, SAME padding)
            float conv = lb[c];
            #pragma unroll
            for (int kh = -1; kh <= 1; ++kh) {
                const int hh = h + kh;
                if (hh < 0 || hh >= Hh) continue;
                #pragma unroll
                for (int kw = -1; kw <= 1; ++kw) {
                    const int ww = w_ + kw;
                    if (ww < 0 || ww >= Ww) continue;
                    conv += x[((long)(b * Hh + hh) * Ww + ww) * Cc + c] *
                            lw[c * 9 + (kh + 1) * 3 + (kw + 1)];
                }
            }
            out[orow + c] = acc[i][j] + pb[c] + conv * mv;
        }
    }
}

// ---------------------------------------------------------------
extern "C" void kernel_launch(void* const* d_in, const int* in_sizes, int n_in,
                              void* d_out, int out_size, void* d_ws, size_t ws_size,
                              hipStream_t stream) {
    const float* x    = (const float*)d_in[0];
    const float* mask = (const float*)d_in[1];
    const float* qw   = (const float*)d_in[2];
    const float* qb   = (const float*)d_in[3];
    const float* pw   = (const float*)d_in[4];
    const float* pb   = (const float*)d_in[5];
    const float* lw   = (const float*)d_in[6];
    const float* lb   = (const float*)d_in[7];
    const float* lsc  = (const float*)d_in[8];
    const float* btab = (const float*)d_in[9];

    unsigned short* qkv  = (unsigned short*)d_ws;                // bf16 [73728][576]
    unsigned short* aout = qkv + (size_t)Mrows * QKVN;           // bf16 [73728][192]

    qkv_gemm<<<dim3(Mrows/64, QKVN/64), dim3(16,16), 0, stream>>>(x, qw, qb, qkv);
    attn_kernel<<<dim3(NWIN * HEADS), dim3(192), 0, stream>>>(qkv, btab, aout);
    proj_lpe<<<dim3(Mrows/64, Cc/64), dim3(16,16), 0, stream>>>(aout, pw, pb, x, lw, lb, lsc, mask,
                                                                (float*)d_out);
}

// Round 4
// 610.091 us; speedup vs baseline: 1.5187x; 1.5187x over previous
//
#include <hip/hip_runtime.h>
#include <hip/hip_bf16.h>

// ---------- constants ----------
constexpr int Bb   = 8;
constexpr int Hh   = 96;
constexpr int Ww   = 96;
constexpr int Cc   = 192;
constexpr int WS   = 12;
constexpr int WS2  = 144;            // 12*12
constexpr int HEADS= 8;
constexpr int HD   = 24;
constexpr int NWIN = Bb * (Hh/WS) * (Ww/WS);   // 512
constexpr int Mrows= NWIN * WS2;               // 73728
constexpr int QKVN = 3 * Cc;                   // 576

typedef __bf16 bf16x8 __attribute__((ext_vector_type(8)));
typedef float  f32x4  __attribute__((ext_vector_type(4)));

constexpr int LDP = 40;   // LDS row stride in bf16 elements (32 + 8 pad -> 80B, banks tile cleanly)

__device__ __forceinline__ float us2f(unsigned short u) {
    unsigned int i = ((unsigned int)u) << 16;
    float f; __builtin_memcpy(&f, &i, 4);
    return f;
}
__device__ __forceinline__ unsigned short f2us(float f) {
    unsigned int i; __builtin_memcpy(&i, &f, 4);
    unsigned int lsb = (i >> 16) & 1u;
    i += 0x7fffu + lsb;
    return (unsigned short)(i >> 16);
}

// ---------------------------------------------------------------
// Kernel 1 (MFMA): qkv = window_partition(x) @ qkv_w^T + qkv_b
// Tile 128(M) x 64(N), BK=32, 4 waves in 2x2. f32 inputs converted
// to bf16 in registers, staged to padded LDS, 16x16x32 bf16 MFMA.
// ---------------------------------------------------------------
__global__ __launch_bounds__(256) void qkv_gemm(
        const float* __restrict__ x,      // f32 [B*N*C]
        const float* __restrict__ w,      // f32 [576][192]
        const float* __restrict__ bias,   // f32 [576]
        unsigned short* __restrict__ qkv) // bf16 [Mrows][576]
{
    __shared__ __bf16 As[128][LDP];
    __shared__ __bf16 Bs[64][LDP];

    const int tid = threadIdx.x;
    const int m0  = blockIdx.x * 128;
    const int n0  = blockIdx.y * 64;

    // ---- staging maps ----
    const int sa_row = tid >> 1;            // 0..127
    const int sa_ks  = (tid & 1) * 16;      // 0 or 16
    const int sb_row = tid >> 2;            // 0..63
    const int sb_ks  = (tid & 3) * 8;       // 0,8,16,24

    // window gather for A row (m0 + sa_row)
    const int m    = m0 + sa_row;
    const int widx = m / WS2;
    const int pos  = m % WS2;
    const int b    = widx >> 6;
    const int wi   = (widx >> 3) & 7;
    const int wj   = widx & 7;
    const long xrow = ((long)((b * Hh + wi * WS + pos / WS) * Ww + wj * WS + pos % WS)) * Cc;
    const long brow = (long)(n0 + sb_row) * Cc;

    // ---- wave/fragment maps ----
    const int lane = tid & 63;
    const int wid  = tid >> 6;
    const int wm   = wid >> 1;              // 0..1 : 64 rows
    const int wn   = wid & 1;               // 0..1 : 32 cols
    const int frow = lane & 15;
    const int kblk = lane >> 4;             // 0..3

    f32x4 acc[4][2];
    #pragma unroll
    for (int i = 0; i < 4; ++i)
        #pragma unroll
        for (int j = 0; j < 2; ++j)
            acc[i][j] = f32x4{0.f, 0.f, 0.f, 0.f};

    for (int k0 = 0; k0 < Cc; k0 += 32) {
        // stage A (f32 -> bf16)
        {
            const float* g = x + xrow + k0 + sa_ks;
            float4 f0 = *reinterpret_cast<const float4*>(g);
            float4 f1 = *reinterpret_cast<const float4*>(g + 4);
            float4 f2 = *reinterpret_cast<const float4*>(g + 8);
            float4 f3 = *reinterpret_cast<const float4*>(g + 12);
            bf16x8 p0, p1;
            p0[0]=(__bf16)f0.x; p0[1]=(__bf16)f0.y; p0[2]=(__bf16)f0.z; p0[3]=(__bf16)f0.w;
            p0[4]=(__bf16)f1.x; p0[5]=(__bf16)f1.y; p0[6]=(__bf16)f1.z; p0[7]=(__bf16)f1.w;
            p1[0]=(__bf16)f2.x; p1[1]=(__bf16)f2.y; p1[2]=(__bf16)f2.z; p1[3]=(__bf16)f2.w;
            p1[4]=(__bf16)f3.x; p1[5]=(__bf16)f3.y; p1[6]=(__bf16)f3.z; p1[7]=(__bf16)f3.w;
            *reinterpret_cast<bf16x8*>(&As[sa_row][sa_ks])     = p0;
            *reinterpret_cast<bf16x8*>(&As[sa_row][sa_ks + 8]) = p1;
        }
        // stage B (f32 -> bf16)
        {
            const float* g = w + brow + k0 + sb_ks;
            float4 f0 = *reinterpret_cast<const float4*>(g);
            float4 f1 = *reinterpret_cast<const float4*>(g + 4);
            bf16x8 p0;
            p0[0]=(__bf16)f0.x; p0[1]=(__bf16)f0.y; p0[2]=(__bf16)f0.z; p0[3]=(__bf16)f0.w;
            p0[4]=(__bf16)f1.x; p0[5]=(__bf16)f1.y; p0[6]=(__bf16)f1.z; p0[7]=(__bf16)f1.w;
            *reinterpret_cast<bf16x8*>(&Bs[sb_row][sb_ks]) = p0;
        }
        __syncthreads();

        bf16x8 a0 = *reinterpret_cast<const bf16x8*>(&As[wm*64 +  0 + frow][kblk*8]);
        bf16x8 a1 = *reinterpret_cast<const bf16x8*>(&As[wm*64 + 16 + frow][kblk*8]);
        bf16x8 a2 = *reinterpret_cast<const bf16x8*>(&As[wm*64 + 32 + frow][kblk*8]);
        bf16x8 a3 = *reinterpret_cast<const bf16x8*>(&As[wm*64 + 48 + frow][kblk*8]);
        bf16x8 b0 = *reinterpret_cast<const bf16x8*>(&Bs[wn*32 +  0 + frow][kblk*8]);
        bf16x8 b1 = *reinterpret_cast<const bf16x8*>(&Bs[wn*32 + 16 + frow][kblk*8]);

        acc[0][0] = __builtin_amdgcn_mfma_f32_16x16x32_bf16(a0, b0, acc[0][0], 0, 0, 0);
        acc[0][1] = __builtin_amdgcn_mfma_f32_16x16x32_bf16(a0, b1, acc[0][1], 0, 0, 0);
        acc[1][0] = __builtin_amdgcn_mfma_f32_16x16x32_bf16(a1, b0, acc[1][0], 0, 0, 0);
        acc[1][1] = __builtin_amdgcn_mfma_f32_16x16x32_bf16(a1, b1, acc[1][1], 0, 0, 0);
        acc[2][0] = __builtin_amdgcn_mfma_f32_16x16x32_bf16(a2, b0, acc[2][0], 0, 0, 0);
        acc[2][1] = __builtin_amdgcn_mfma_f32_16x16x32_bf16(a2, b1, acc[2][1], 0, 0, 0);
        acc[3][0] = __builtin_amdgcn_mfma_f32_16x16x32_bf16(a3, b0, acc[3][0], 0, 0, 0);
        acc[3][1] = __builtin_amdgcn_mfma_f32_16x16x32_bf16(a3, b1, acc[3][1], 0, 0, 0);
        __syncthreads();
    }

    // epilogue: +bias, store bf16.  C row=(lane>>4)*4+r, col=lane&15
    const int lrow = lane >> 4, lcol = lane & 15;
    #pragma unroll
    for (int fn = 0; fn < 2; ++fn) {
        const int c = n0 + wn*32 + fn*16 + lcol;
        const float bv = bias[c];
        #pragma unroll
        for (int fm = 0; fm < 4; ++fm) {
            const int rbase = m0 + wm*64 + fm*16 + lrow*4;
            #pragma unroll
            for (int r = 0; r < 4; ++r)
                qkv[(long)(rbase + r) * QKVN + c] = f2us(acc[fm][fn][r] + bv);
        }
    }
}

// ---------------------------------------------------------------
// Kernel 2: per-(window, head) attention with online softmax.
// (unchanged from round 2 — measure its true cost this round)
// ---------------------------------------------------------------
__global__ __launch_bounds__(192) void attn_kernel(
        const unsigned short* __restrict__ qkv,    // bf16 [Mrows][576]
        const float* __restrict__ btab,            // f32 [529][8]
        unsigned short* __restrict__ aout)         // bf16 [Mrows][192]
{
    __shared__ float Ks[WS2][HD];
    __shared__ float Vs[WS2][HD];
    __shared__ float Bh[529];

    const int blk  = blockIdx.x;     // 0..4095
    const int win  = blk >> 3;
    const int head = blk & 7;
    const int tid  = threadIdx.x;

    const long base = (long)win * WS2 * QKVN;
    const int hoff = head * HD;

    for (int e = tid; e < WS2 * HD; e += 192) {
        const int p = e / HD, d = e % HD;
        Ks[p][d] = us2f(qkv[base + (long)p * QKVN + Cc     + hoff + d]);
        Vs[p][d] = us2f(qkv[base + (long)p * QKVN + 2*Cc   + hoff + d]);
    }
    for (int e = tid; e < 529; e += 192)
        Bh[e] = btab[e * HEADS + head];
    __syncthreads();

    if (tid < WS2) {
        const float scale = 0.2041241452319315f;   // 1/sqrt(24)
        float qf[HD];
        #pragma unroll
        for (int d = 0; d < HD; ++d)
            qf[d] = us2f(qkv[base + (long)tid * QKVN + hoff + d]) * scale;

        const int rq = tid / WS, sq = tid % WS;
        float mmax = -1e30f, l = 0.f;
        float out[HD];
        #pragma unroll
        for (int d = 0; d < HD; ++d) out[d] = 0.f;

        for (int j = 0; j < WS2; ++j) {
            float dot = 0.f;
            #pragma unroll
            for (int d = 0; d < HD; ++d) dot += qf[d] * Ks[j][d];
            const int rj = j / WS, sj = j % WS;
            dot += Bh[(rq - rj + 11) * 23 + (sq - sj + 11)];
            float p;
            if (dot > mmax) {
                const float c = __expf(mmax - dot);
                l *= c;
                #pragma unroll
                for (int d = 0; d < HD; ++d) out[d] *= c;
                mmax = dot;
                p = 1.f;
            } else {
                p = __expf(dot - mmax);
            }
            l += p;
            #pragma unroll
            for (int d = 0; d < HD; ++d) out[d] += p * Vs[j][d];
        }
        const float inv = 1.f / l;
        const long ob = (long)(win * WS2 + tid) * Cc + hoff;
        #pragma unroll
        for (int d = 0; d < HD; ++d)
            aout[ob + d] = f2us(out[d] * inv);
    }
}

// ---------------------------------------------------------------
// Kernel 3 (MFMA): out = window_reverse(aout @ proj_w^T + proj_b) + LPE
// Tile 128x64, BK=32; A already bf16; epilogue fuses window-reverse
// scatter + depthwise 3x3 conv + mask gating, f32 output.
// ---------------------------------------------------------------
__global__ __launch_bounds__(256) void proj_lpe(
        const unsigned short* __restrict__ aout,   // bf16 [Mrows][192]
        const float* __restrict__ pw,              // f32 [192][192]
        const float* __restrict__ pb,              // f32 [192]
        const float* __restrict__ x,               // f32 [B*N*C]
        const float* __restrict__ lw,              // f32 [192][9]
        const float* __restrict__ lb,              // f32 [192]
        const float* __restrict__ lsc,             // f32 [1]
        const float* __restrict__ mask,            // f32 [B][H][W]
        float* __restrict__ out)                   // f32 [B*N*C]
{
    __shared__ __bf16 As[128][LDP];
    __shared__ __bf16 Bs[64][LDP];

    const int tid = threadIdx.x;
    const int m0  = blockIdx.x * 128;
    const int n0  = blockIdx.y * 64;

    const int sa_row = tid >> 1;
    const int sa_ks  = (tid & 1) * 16;
    const int sb_row = tid >> 2;
    const int sb_ks  = (tid & 3) * 8;

    const long arow = (long)(m0 + sa_row) * Cc;
    const long brow = (long)(n0 + sb_row) * Cc;

    const int lane = tid & 63;
    const int wid  = tid >> 6;
    const int wm   = wid >> 1;
    const int wn   = wid & 1;
    const int frow = lane & 15;
    const int kblk = lane >> 4;

    f32x4 acc[4][2];
    #pragma unroll
    for (int i = 0; i < 4; ++i)
        #pragma unroll
        for (int j = 0; j < 2; ++j)
            acc[i][j] = f32x4{0.f, 0.f, 0.f, 0.f};

    for (int k0 = 0; k0 < Cc; k0 += 32) {
        // stage A (already bf16): 16 elements = 2x 16B
        {
            const unsigned short* g = aout + arow + k0 + sa_ks;
            uint4 v0 = *reinterpret_cast<const uint4*>(g);
            uint4 v1 = *reinterpret_cast<const uint4*>(g + 8);
            *reinterpret_cast<uint4*>(&As[sa_row][sa_ks])     = v0;
            *reinterpret_cast<uint4*>(&As[sa_row][sa_ks + 8]) = v1;
        }
        // stage B (f32 -> bf16)
        {
            const float* g = pw + brow + k0 + sb_ks;
            float4 f0 = *reinterpret_cast<const float4*>(g);
            float4 f1 = *reinterpret_cast<const float4*>(g + 4);
            bf16x8 p0;
            p0[0]=(__bf16)f0.x; p0[1]=(__bf16)f0.y; p0[2]=(__bf16)f0.z; p0[3]=(__bf16)f0.w;
            p0[4]=(__bf16)f1.x; p0[5]=(__bf16)f1.y; p0[6]=(__bf16)f1.z; p0[7]=(__bf16)f1.w;
            *reinterpret_cast<bf16x8*>(&Bs[sb_row][sb_ks]) = p0;
        }
        __syncthreads();

        bf16x8 a0 = *reinterpret_cast<const bf16x8*>(&As[wm*64 +  0 + frow][kblk*8]);
        bf16x8 a1 = *reinterpret_cast<const bf16x8*>(&As[wm*64 + 16 + frow][kblk*8]);
        bf16x8 a2 = *reinterpret_cast<const bf16x8*>(&As[wm*64 + 32 + frow][kblk*8]);
        bf16x8 a3 = *reinterpret_cast<const bf16x8*>(&As[wm*64 + 48 + frow][kblk*8]);
        bf16x8 b0 = *reinterpret_cast<const bf16x8*>(&Bs[wn*32 +  0 + frow][kblk*8]);
        bf16x8 b1 = *reinterpret_cast<const bf16x8*>(&Bs[wn*32 + 16 + frow][kblk*8]);

        acc[0][0] = __builtin_amdgcn_mfma_f32_16x16x32_bf16(a0, b0, acc[0][0], 0, 0, 0);
        acc[0][1] = __builtin_amdgcn_mfma_f32_16x16x32_bf16(a0, b1, acc[0][1], 0, 0, 0);
        acc[1][0] = __builtin_amdgcn_mfma_f32_16x16x32_bf16(a1, b0, acc[1][0], 0, 0, 0);
        acc[1][1] = __builtin_amdgcn_mfma_f32_16x16x32_bf16(a1, b1, acc[1][1], 0, 0, 0);
        acc[2][0] = __builtin_amdgcn_mfma_f32_16x16x32_bf16(a2, b0, acc[2][0], 0, 0, 0);
        acc[2][1] = __builtin_amdgcn_mfma_f32_16x16x32_bf16(a2, b1, acc[2][1], 0, 0, 0);
        acc[3][0] = __builtin_amdgcn_mfma_f32_16x16x32_bf16(a3, b0, acc[3][0], 0, 0, 0);
        acc[3][1] = __builtin_amdgcn_mfma_f32_16x16x32_bf16(a3, b1, acc[3][1], 0, 0, 0);
        __syncthreads();
    }

    const float lscale = lsc[0];
    const int lrow = lane >> 4, lcol = lane & 15;

    #pragma unroll
    for (int fm = 0; fm < 4; ++fm) {
        #pragma unroll
        for (int r = 0; r < 4; ++r) {
            const int mrow = m0 + wm*64 + fm*16 + lrow*4 + r;
            const int widx = mrow / WS2;
            const int pos  = mrow % WS2;
            const int b    = widx >> 6;
            const int wi   = (widx >> 3) & 7;
            const int wj   = widx & 7;
            const int h    = wi * WS + pos / WS;
            const int w_   = wj * WS + pos % WS;
            const float mv = mask[(b * Hh + h) * Ww + w_] * lscale;
            const long orow = ((long)(b * Hh + h) * Ww + w_) * Cc;

            #pragma unroll
            for (int fn = 0; fn < 2; ++fn) {
                const int c = n0 + wn*32 + fn*16 + lcol;
                float conv = lb[c];
                #pragma unroll
                for (int kh = -1; kh <= 1; ++kh) {
                    const int hh = h + kh;
                    if (hh < 0 || hh >= Hh) continue;
                    #pragma unroll
                    for (int kw = -1; kw <= 1; ++kw) {
                        const int ww = w_ + kw;
                        if (ww < 0 || ww >= Ww) continue;
                        conv += x[((long)(b * Hh + hh) * Ww + ww) * Cc + c] *
                                lw[c * 9 + (kh + 1) * 3 + (kw + 1)];
                    }
                }
                out[orow + c] = acc[fm][fn][r] + pb[c] + conv * mv;
            }
        }
    }
}

// ---------------------------------------------------------------
extern "C" void kernel_launch(void* const* d_in, const int* in_sizes, int n_in,
                              void* d_out, int out_size, void* d_ws, size_t ws_size,
                              hipStream_t stream) {
    const float* x    = (const float*)d_in[0];
    const float* mask = (const float*)d_in[1];
    const float* qw   = (const float*)d_in[2];
    const float* qb   = (const float*)d_in[3];
    const float* pw   = (const float*)d_in[4];
    const float* pb   = (const float*)d_in[5];
    const float* lw   = (const float*)d_in[6];
    const float* lb   = (const float*)d_in[7];
    const float* lsc  = (const float*)d_in[8];
    const float* btab = (const float*)d_in[9];

    unsigned short* qkv  = (unsigned short*)d_ws;                // bf16 [73728][576]
    unsigned short* aout = qkv + (size_t)Mrows * QKVN;           // bf16 [73728][192]

    qkv_gemm<<<dim3(Mrows/128, QKVN/64), dim3(256), 0, stream>>>(x, qw, qb, qkv);
    attn_kernel<<<dim3(NWIN * HEADS), dim3(192), 0, stream>>>(qkv, btab, aout);
    proj_lpe<<<dim3(Mrows/128, Cc/64), dim3(256), 0, stream>>>(aout, pw, pb, x, lw, lb, lsc, mask,
                                                               (float*)d_out);
}

// Round 5
// 451.945 us; speedup vs baseline: 2.0501x; 1.3499x over previous
//
#include <hip/hip_runtime.h>
#include <hip/hip_bf16.h>

// ---------- constants ----------
constexpr int Bb   = 8;
constexpr int Hh   = 96;
constexpr int Ww   = 96;
constexpr int Cc   = 192;
constexpr int WS   = 12;
constexpr int WS2  = 144;            // 12*12
constexpr int HEADS= 8;
constexpr int HD   = 24;
constexpr int NWIN = Bb * (Hh/WS) * (Ww/WS);   // 512
constexpr int Mrows= NWIN * WS2;               // 73728
constexpr int QKVN = 3 * Cc;                   // 576

typedef __bf16 bf16x8 __attribute__((ext_vector_type(8)));
typedef float  f32x4  __attribute__((ext_vector_type(4)));

constexpr int LDP = 40;   // GEMM LDS row stride (bf16): 80B -> 2-way bank aliasing = free

__device__ __forceinline__ float us2f(unsigned short u) {
    unsigned int i = ((unsigned int)u) << 16;
    float f; __builtin_memcpy(&f, &i, 4);
    return f;
}
__device__ __forceinline__ unsigned short f2us(float f) {
    unsigned int i; __builtin_memcpy(&i, &f, 4);
    unsigned int lsb = (i >> 16) & 1u;
    i += 0x7fffu + lsb;
    return (unsigned short)(i >> 16);
}

// ---------------------------------------------------------------
// Kernel 1 (MFMA): qkv = window_partition(x) @ qkv_w^T + qkv_b
// ---------------------------------------------------------------
__global__ __launch_bounds__(256) void qkv_gemm(
        const float* __restrict__ x,      // f32 [B*N*C]
        const float* __restrict__ w,      // f32 [576][192]
        const float* __restrict__ bias,   // f32 [576]
        unsigned short* __restrict__ qkv) // bf16 [Mrows][576]
{
    __shared__ __bf16 As[128][LDP];
    __shared__ __bf16 Bs[64][LDP];

    const int tid = threadIdx.x;
    const int m0  = blockIdx.x * 128;
    const int n0  = blockIdx.y * 64;

    const int sa_row = tid >> 1;
    const int sa_ks  = (tid & 1) * 16;
    const int sb_row = tid >> 2;
    const int sb_ks  = (tid & 3) * 8;

    const int m    = m0 + sa_row;
    const int widx = m / WS2;
    const int pos  = m % WS2;
    const int b    = widx >> 6;
    const int wi   = (widx >> 3) & 7;
    const int wj   = widx & 7;
    const long xrow = ((long)((b * Hh + wi * WS + pos / WS) * Ww + wj * WS + pos % WS)) * Cc;
    const long brow = (long)(n0 + sb_row) * Cc;

    const int lane = tid & 63;
    const int wid  = tid >> 6;
    const int wm   = wid >> 1;
    const int wn   = wid & 1;
    const int frow = lane & 15;
    const int kblk = lane >> 4;

    f32x4 acc[4][2];
    #pragma unroll
    for (int i = 0; i < 4; ++i)
        #pragma unroll
        for (int j = 0; j < 2; ++j)
            acc[i][j] = f32x4{0.f, 0.f, 0.f, 0.f};

    for (int k0 = 0; k0 < Cc; k0 += 32) {
        {
            const float* g = x + xrow + k0 + sa_ks;
            float4 f0 = *reinterpret_cast<const float4*>(g);
            float4 f1 = *reinterpret_cast<const float4*>(g + 4);
            float4 f2 = *reinterpret_cast<const float4*>(g + 8);
            float4 f3 = *reinterpret_cast<const float4*>(g + 12);
            bf16x8 p0, p1;
            p0[0]=(__bf16)f0.x; p0[1]=(__bf16)f0.y; p0[2]=(__bf16)f0.z; p0[3]=(__bf16)f0.w;
            p0[4]=(__bf16)f1.x; p0[5]=(__bf16)f1.y; p0[6]=(__bf16)f1.z; p0[7]=(__bf16)f1.w;
            p1[0]=(__bf16)f2.x; p1[1]=(__bf16)f2.y; p1[2]=(__bf16)f2.z; p1[3]=(__bf16)f2.w;
            p1[4]=(__bf16)f3.x; p1[5]=(__bf16)f3.y; p1[6]=(__bf16)f3.z; p1[7]=(__bf16)f3.w;
            *reinterpret_cast<bf16x8*>(&As[sa_row][sa_ks])     = p0;
            *reinterpret_cast<bf16x8*>(&As[sa_row][sa_ks + 8]) = p1;
        }
        {
            const float* g = w + brow + k0 + sb_ks;
            float4 f0 = *reinterpret_cast<const float4*>(g);
            float4 f1 = *reinterpret_cast<const float4*>(g + 4);
            bf16x8 p0;
            p0[0]=(__bf16)f0.x; p0[1]=(__bf16)f0.y; p0[2]=(__bf16)f0.z; p0[3]=(__bf16)f0.w;
            p0[4]=(__bf16)f1.x; p0[5]=(__bf16)f1.y; p0[6]=(__bf16)f1.z; p0[7]=(__bf16)f1.w;
            *reinterpret_cast<bf16x8*>(&Bs[sb_row][sb_ks]) = p0;
        }
        __syncthreads();

        bf16x8 a0 = *reinterpret_cast<const bf16x8*>(&As[wm*64 +  0 + frow][kblk*8]);
        bf16x8 a1 = *reinterpret_cast<const bf16x8*>(&As[wm*64 + 16 + frow][kblk*8]);
        bf16x8 a2 = *reinterpret_cast<const bf16x8*>(&As[wm*64 + 32 + frow][kblk*8]);
        bf16x8 a3 = *reinterpret_cast<const bf16x8*>(&As[wm*64 + 48 + frow][kblk*8]);
        bf16x8 b0 = *reinterpret_cast<const bf16x8*>(&Bs[wn*32 +  0 + frow][kblk*8]);
        bf16x8 b1 = *reinterpret_cast<const bf16x8*>(&Bs[wn*32 + 16 + frow][kblk*8]);

        acc[0][0] = __builtin_amdgcn_mfma_f32_16x16x32_bf16(a0, b0, acc[0][0], 0, 0, 0);
        acc[0][1] = __builtin_amdgcn_mfma_f32_16x16x32_bf16(a0, b1, acc[0][1], 0, 0, 0);
        acc[1][0] = __builtin_amdgcn_mfma_f32_16x16x32_bf16(a1, b0, acc[1][0], 0, 0, 0);
        acc[1][1] = __builtin_amdgcn_mfma_f32_16x16x32_bf16(a1, b1, acc[1][1], 0, 0, 0);
        acc[2][0] = __builtin_amdgcn_mfma_f32_16x16x32_bf16(a2, b0, acc[2][0], 0, 0, 0);
        acc[2][1] = __builtin_amdgcn_mfma_f32_16x16x32_bf16(a2, b1, acc[2][1], 0, 0, 0);
        acc[3][0] = __builtin_amdgcn_mfma_f32_16x16x32_bf16(a3, b0, acc[3][0], 0, 0, 0);
        acc[3][1] = __builtin_amdgcn_mfma_f32_16x16x32_bf16(a3, b1, acc[3][1], 0, 0, 0);
        __syncthreads();
    }

    const int lrow = lane >> 4, lcol = lane & 15;
    #pragma unroll
    for (int fn = 0; fn < 2; ++fn) {
        const int c = n0 + wn*32 + fn*16 + lcol;
        const float bv = bias[c];
        #pragma unroll
        for (int fm = 0; fm < 4; ++fm) {
            const int rbase = m0 + wm*64 + fm*16 + lrow*4;
            #pragma unroll
            for (int r = 0; r < 4; ++r)
                qkv[(long)(rbase + r) * QKVN + c] = f2us(acc[fm][fn][r] + bv);
        }
    }
}

// ---------------------------------------------------------------
// Kernel 2 (MFMA): per-(window, head) attention.
// 192 threads = 3 waves, each wave owns 3 query-tiles of 16 rows.
// S^T = mfma(K, Q) so q is lane-local (col=lane&15); softmax needs
// only a 4-lane shfl_xor reduce; P -> wave-private LDS -> PV MFMA.
// ---------------------------------------------------------------
__global__ __launch_bounds__(192) void attn_kernel(
        const unsigned short* __restrict__ qkv,    // bf16 [Mrows][576]
        const float* __restrict__ btab,            // f32 [529][8]
        unsigned short* __restrict__ aout)         // bf16 [Mrows][192]
{
    __shared__ unsigned short Klds[WS2][40];   // d padded 24->32 (cols 24..31 zero)
    __shared__ unsigned short Qlds[WS2][40];
    __shared__ unsigned short Vt[32][168];     // [d][kv], kv padded 144->160 zero
    __shared__ unsigned short Pl[3][16][168];  // per-wave P slab [q][kv]
    __shared__ float Bh[529];
    __shared__ unsigned short klut[WS2];       // rkv*23 + skv
    __shared__ float l_inv[3][16];

    const int win  = blockIdx.x;
    const int head = blockIdx.y;
    const int tid  = threadIdx.x;

    const long base = (long)win * WS2 * QKVN;  // element offset into qkv
    const int hoff  = head * HD;

    // ---- staging ----
    if (tid < WS2) {
        const uint4* qs = reinterpret_cast<const uint4*>(qkv + base + (long)tid * QKVN + hoff);
        const uint4* ks = reinterpret_cast<const uint4*>(qkv + base + (long)tid * QKVN + Cc + hoff);
        const uint4* vs = reinterpret_cast<const uint4*>(qkv + base + (long)tid * QKVN + 2*Cc + hoff);
        uint4 q0 = qs[0], q1 = qs[1], q2 = qs[2];
        uint4 k0 = ks[0], k1 = ks[1], k2 = ks[2];
        uint4 v0 = vs[0], v1 = vs[1], v2 = vs[2];
        *reinterpret_cast<uint4*>(&Qlds[tid][0])  = q0;
        *reinterpret_cast<uint4*>(&Qlds[tid][8])  = q1;
        *reinterpret_cast<uint4*>(&Qlds[tid][16]) = q2;
        *reinterpret_cast<uint4*>(&Qlds[tid][24]) = uint4{0,0,0,0};
        *reinterpret_cast<uint4*>(&Klds[tid][0])  = k0;
        *reinterpret_cast<uint4*>(&Klds[tid][8])  = k1;
        *reinterpret_cast<uint4*>(&Klds[tid][16]) = k2;
        *reinterpret_cast<uint4*>(&Klds[tid][24]) = uint4{0,0,0,0};
        unsigned short vr[24];
        __builtin_memcpy(&vr[0],  &v0, 16);
        __builtin_memcpy(&vr[8],  &v1, 16);
        __builtin_memcpy(&vr[16], &v2, 16);
        #pragma unroll
        for (int d = 0; d < HD; ++d)
            Vt[d][tid] = vr[d];
    }
    // zero pads of Vt: rows 24..31 (cols 0..159), rows 0..23 cols 144..159
    for (int e = tid; e < 8 * 160; e += 192)
        Vt[24 + e / 160][e % 160] = 0;
    for (int e = tid; e < 24 * 16; e += 192)
        Vt[e / 16][144 + (e & 15)] = 0;
    for (int e = tid; e < 529; e += 192)
        Bh[e] = btab[e * HEADS + head];
    if (tid < WS2)
        klut[tid] = (unsigned short)((tid / WS) * 23 + (tid % WS));
    __syncthreads();

    const int wv   = tid >> 6;       // wave 0..2
    const int lane = tid & 63;
    const int qcol = lane & 15;      // q within tile (lane-local!)
    const int g    = lane >> 4;      // 0..3

    // zero P pad cols 144..159 (wave-private slab)
    #pragma unroll
    for (int i = 0; i < 4; ++i) {
        const int e = lane + i * 64;
        Pl[wv][e >> 4][144 + (e & 15)] = 0;
    }

    const float scale = 0.2041241452319315f;   // 1/sqrt(24)

    #pragma unroll
    for (int ti = 0; ti < 3; ++ti) {
        const int qt = wv * 3 + ti;

        // ---- QK^T: 9 S^T tiles ----
        bf16x8 qb = *reinterpret_cast<const bf16x8*>(&Qlds[qt*16 + qcol][g*8]);
        f32x4 s[9];
        #pragma unroll
        for (int t = 0; t < 9; ++t) {
            bf16x8 ka = *reinterpret_cast<const bf16x8*>(&Klds[t*16 + qcol][g*8]);
            s[t] = __builtin_amdgcn_mfma_f32_16x16x32_bf16(ka, qb,
                     f32x4{0.f,0.f,0.f,0.f}, 0, 0, 0);
        }
        // wait: in C layout col=lane&15 is the B(=Q) row ✓, row=(lane>>4)*4+r is A(=K) row.
        // each lane: q = qcol fixed, kv = t*16 + g*4 + r

        // ---- softmax (row spread over 4 lanes: qcol, +16, +32, +48) ----
        const int qpos = qt * 16 + qcol;
        const float bbase = (float)((qpos / WS + 11) * 23 + (qpos % WS + 11));
        float sv[9][4];
        float mx = -1e30f;
        #pragma unroll
        for (int t = 0; t < 9; ++t)
            #pragma unroll
            for (int r = 0; r < 4; ++r) {
                const int kv = t*16 + g*4 + r;
                const int rel = (int)bbase - (int)klut[kv];
                const float v = s[t][r] * scale + Bh[rel];
                sv[t][r] = v;
                mx = fmaxf(mx, v);
            }
        mx = fmaxf(mx, __shfl_xor(mx, 16));
        mx = fmaxf(mx, __shfl_xor(mx, 32));
        float sum = 0.f;
        #pragma unroll
        for (int t = 0; t < 9; ++t)
            #pragma unroll
            for (int r = 0; r < 4; ++r) {
                const float p = __expf(sv[t][r] - mx);
                sv[t][r] = p;
                sum += p;
            }
        sum += __shfl_xor(sum, 16);
        sum += __shfl_xor(sum, 32);
        if (g == 0)
            l_inv[wv][qcol] = 1.f / sum;

        // ---- P -> LDS (bf16) ----
        #pragma unroll
        for (int t = 0; t < 9; ++t)
            #pragma unroll
            for (int r = 0; r < 4; ++r)
                Pl[wv][qcol][t*16 + g*4 + r] = f2us(sv[t][r]);

        // ---- PV: O[q][d], 5 K-steps x 2 d-tiles ----
        f32x4 o0 = {0.f,0.f,0.f,0.f}, o1 = {0.f,0.f,0.f,0.f};
        #pragma unroll
        for (int ks = 0; ks < 5; ++ks) {
            bf16x8 pa  = *reinterpret_cast<const bf16x8*>(&Pl[wv][qcol][ks*32 + g*8]);
            bf16x8 vb0 = *reinterpret_cast<const bf16x8*>(&Vt[qcol     ][ks*32 + g*8]);
            bf16x8 vb1 = *reinterpret_cast<const bf16x8*>(&Vt[16 + qcol][ks*32 + g*8]);
            o0 = __builtin_amdgcn_mfma_f32_16x16x32_bf16(pa, vb0, o0, 0, 0, 0);
            o1 = __builtin_amdgcn_mfma_f32_16x16x32_bf16(pa, vb1, o1, 0, 0, 0);
        }

        // ---- epilogue: lane holds q rows g*4+idx, d = qcol (tile0) / 16+qcol (tile1)
        #pragma unroll
        for (int idx = 0; idx < 4; ++idx) {
            const int qrow = qt*16 + g*4 + idx;
            const float li = l_inv[wv][g*4 + idx];
            const long ob = (long)(win * WS2 + qrow) * Cc + hoff;
            aout[ob + qcol] = f2us(o0[idx] * li);
            if (qcol < 8)
                aout[ob + 16 + qcol] = f2us(o1[idx] * li);
        }
    }
}

// ---------------------------------------------------------------
// Kernel 3 (MFMA): out = window_reverse(aout @ proj_w^T + proj_b) + LPE
// ---------------------------------------------------------------
__global__ __launch_bounds__(256) void proj_lpe(
        const unsigned short* __restrict__ aout,   // bf16 [Mrows][192]
        const float* __restrict__ pw,              // f32 [192][192]
        const float* __restrict__ pb,              // f32 [192]
        const float* __restrict__ x,               // f32 [B*N*C]
        const float* __restrict__ lw,              // f32 [192][9]
        const float* __restrict__ lb,              // f32 [192]
        const float* __restrict__ lsc,             // f32 [1]
        const float* __restrict__ mask,            // f32 [B][H][W]
        float* __restrict__ out)                   // f32 [B*N*C]
{
    __shared__ __bf16 As[128][LDP];
    __shared__ __bf16 Bs[64][LDP];

    const int tid = threadIdx.x;
    const int m0  = blockIdx.x * 128;
    const int n0  = blockIdx.y * 64;

    const int sa_row = tid >> 1;
    const int sa_ks  = (tid & 1) * 16;
    const int sb_row = tid >> 2;
    const int sb_ks  = (tid & 3) * 8;

    const long arow = (long)(m0 + sa_row) * Cc;
    const long brow = (long)(n0 + sb_row) * Cc;

    const int lane = tid & 63;
    const int wid  = tid >> 6;
    const int wm   = wid >> 1;
    const int wn   = wid & 1;
    const int frow = lane & 15;
    const int kblk = lane >> 4;

    f32x4 acc[4][2];
    #pragma unroll
    for (int i = 0; i < 4; ++i)
        #pragma unroll
        for (int j = 0; j < 2; ++j)
            acc[i][j] = f32x4{0.f, 0.f, 0.f, 0.f};

    for (int k0 = 0; k0 < Cc; k0 += 32) {
        {
            const unsigned short* g = aout + arow + k0 + sa_ks;
            uint4 v0 = *reinterpret_cast<const uint4*>(g);
            uint4 v1 = *reinterpret_cast<const uint4*>(g + 8);
            *reinterpret_cast<uint4*>(&As[sa_row][sa_ks])     = v0;
            *reinterpret_cast<uint4*>(&As[sa_row][sa_ks + 8]) = v1;
        }
        {
            const float* g = pw + brow + k0 + sb_ks;
            float4 f0 = *reinterpret_cast<const float4*>(g);
            float4 f1 = *reinterpret_cast<const float4*>(g + 4);
            bf16x8 p0;
            p0[0]=(__bf16)f0.x; p0[1]=(__bf16)f0.y; p0[2]=(__bf16)f0.z; p0[3]=(__bf16)f0.w;
            p0[4]=(__bf16)f1.x; p0[5]=(__bf16)f1.y; p0[6]=(__bf16)f1.z; p0[7]=(__bf16)f1.w;
            *reinterpret_cast<bf16x8*>(&Bs[sb_row][sb_ks]) = p0;
        }
        __syncthreads();

        bf16x8 a0 = *reinterpret_cast<const bf16x8*>(&As[wm*64 +  0 + frow][kblk*8]);
        bf16x8 a1 = *reinterpret_cast<const bf16x8*>(&As[wm*64 + 16 + frow][kblk*8]);
        bf16x8 a2 = *reinterpret_cast<const bf16x8*>(&As[wm*64 + 32 + frow][kblk*8]);
        bf16x8 a3 = *reinterpret_cast<const bf16x8*>(&As[wm*64 + 48 + frow][kblk*8]);
        bf16x8 b0 = *reinterpret_cast<const bf16x8*>(&Bs[wn*32 +  0 + frow][kblk*8]);
        bf16x8 b1 = *reinterpret_cast<const bf16x8*>(&Bs[wn*32 + 16 + frow][kblk*8]);

        acc[0][0] = __builtin_amdgcn_mfma_f32_16x16x32_bf16(a0, b0, acc[0][0], 0, 0, 0);
        acc[0][1] = __builtin_amdgcn_mfma_f32_16x16x32_bf16(a0, b1, acc[0][1], 0, 0, 0);
        acc[1][0] = __builtin_amdgcn_mfma_f32_16x16x32_bf16(a1, b0, acc[1][0], 0, 0, 0);
        acc[1][1] = __builtin_amdgcn_mfma_f32_16x16x32_bf16(a1, b1, acc[1][1], 0, 0, 0);
        acc[2][0] = __builtin_amdgcn_mfma_f32_16x16x32_bf16(a2, b0, acc[2][0], 0, 0, 0);
        acc[2][1] = __builtin_amdgcn_mfma_f32_16x16x32_bf16(a2, b1, acc[2][1], 0, 0, 0);
        acc[3][0] = __builtin_amdgcn_mfma_f32_16x16x32_bf16(a3, b0, acc[3][0], 0, 0, 0);
        acc[3][1] = __builtin_amdgcn_mfma_f32_16x16x32_bf16(a3, b1, acc[3][1], 0, 0, 0);
        __syncthreads();
    }

    const float lscale = lsc[0];
    const int lrow = lane >> 4, lcol = lane & 15;

    #pragma unroll
    for (int fm = 0; fm < 4; ++fm) {
        #pragma unroll
        for (int r = 0; r < 4; ++r) {
            const int mrow = m0 + wm*64 + fm*16 + lrow*4 + r;
            const int widx = mrow / WS2;
            const int pos  = mrow % WS2;
            const int b    = widx >> 6;
            const int wi   = (widx >> 3) & 7;
            const int wj   = widx & 7;
            const int h    = wi * WS + pos / WS;
            const int w_   = wj * WS + pos % WS;
            const float mv = mask[(b * Hh + h) * Ww + w_] * lscale;
            const long orow = ((long)(b * Hh + h) * Ww + w_) * Cc;

            #pragma unroll
            for (int fn = 0; fn < 2; ++fn) {
                const int c = n0 + wn*32 + fn*16 + lcol;
                float conv = lb[c];
                #pragma unroll
                for (int kh = -1; kh <= 1; ++kh) {
                    const int hh = h + kh;
                    if (hh < 0 || hh >= Hh) continue;
                    #pragma unroll
                    for (int kw = -1; kw <= 1; ++kw) {
                        const int ww = w_ + kw;
                        if (ww < 0 || ww >= Ww) continue;
                        conv += x[((long)(b * Hh + hh) * Ww + ww) * Cc + c] *
                                lw[c * 9 + (kh + 1) * 3 + (kw + 1)];
                    }
                }
                out[orow + c] = acc[fm][fn][r] + pb[c] + conv * mv;
            }
        }
    }
}

// ---------------------------------------------------------------
extern "C" void kernel_launch(void* const* d_in, const int* in_sizes, int n_in,
                              void* d_out, int out_size, void* d_ws, size_t ws_size,
                              hipStream_t stream) {
    const float* x    = (const float*)d_in[0];
    const float* mask = (const float*)d_in[1];
    const float* qw   = (const float*)d_in[2];
    const float* qb   = (const float*)d_in[3];
    const float* pw   = (const float*)d_in[4];
    const float* pb   = (const float*)d_in[5];
    const float* lw   = (const float*)d_in[6];
    const float* lb   = (const float*)d_in[7];
    const float* lsc  = (const float*)d_in[8];
    const float* btab = (const float*)d_in[9];

    unsigned short* qkv  = (unsigned short*)d_ws;                // bf16 [73728][576]
    unsigned short* aout = qkv + (size_t)Mrows * QKVN;           // bf16 [73728][192]

    qkv_gemm<<<dim3(Mrows/128, QKVN/64), dim3(256), 0, stream>>>(x, qw, qb, qkv);
    attn_kernel<<<dim3(NWIN, HEADS), dim3(192), 0, stream>>>(qkv, btab, aout);
    proj_lpe<<<dim3(Mrows/128, Cc/64), dim3(256), 0, stream>>>(aout, pw, pb, x, lw, lb, lsc, mask,
                                                               (float*)d_out);
}

// Round 6
// 340.511 us; speedup vs baseline: 2.7211x; 1.3273x over previous
//
#include <hip/hip_runtime.h>
#include <hip/hip_bf16.h>

// ---------- constants ----------
constexpr int Bb   = 8;
constexpr int Hh   = 96;
constexpr int Ww   = 96;
constexpr int Cc   = 192;
constexpr int WS   = 12;
constexpr int WS2  = 144;            // 12*12
constexpr int HEADS= 8;
constexpr int HD   = 24;
constexpr int NWIN = Bb * (Hh/WS) * (Ww/WS);   // 512
constexpr int Mrows= NWIN * WS2;               // 73728
constexpr int QKVN = 3 * Cc;                   // 576

typedef __bf16 bf16x8 __attribute__((ext_vector_type(8)));
typedef float  f32x4  __attribute__((ext_vector_type(4)));

constexpr int LDP = 40;   // GEMM LDS row stride (bf16): 80B -> 2-way bank aliasing = free

__device__ __forceinline__ float us2f(unsigned short u) {
    unsigned int i = ((unsigned int)u) << 16;
    float f; __builtin_memcpy(&f, &i, 4);
    return f;
}
__device__ __forceinline__ unsigned short f2us(float f) {
    unsigned int i; __builtin_memcpy(&i, &f, 4);
    unsigned int lsb = (i >> 16) & 1u;
    i += 0x7fffu + lsb;
    return (unsigned short)(i >> 16);
}

// ---------------------------------------------------------------
// Kernel 1 (MFMA): qkv = window_partition(x) @ qkv_w^T + qkv_b
// ---------------------------------------------------------------
__global__ __launch_bounds__(256) void qkv_gemm(
        const float* __restrict__ x,      // f32 [B*N*C]
        const float* __restrict__ w,      // f32 [576][192]
        const float* __restrict__ bias,   // f32 [576]
        unsigned short* __restrict__ qkv) // bf16 [Mrows][576]
{
    __shared__ __bf16 As[128][LDP];
    __shared__ __bf16 Bs[64][LDP];

    const int tid = threadIdx.x;
    const int m0  = blockIdx.x * 128;
    const int n0  = blockIdx.y * 64;

    const int sa_row = tid >> 1;
    const int sa_ks  = (tid & 1) * 16;
    const int sb_row = tid >> 2;
    const int sb_ks  = (tid & 3) * 8;

    const int m    = m0 + sa_row;
    const int widx = m / WS2;
    const int pos  = m % WS2;
    const int b    = widx >> 6;
    const int wi   = (widx >> 3) & 7;
    const int wj   = widx & 7;
    const long xrow = ((long)((b * Hh + wi * WS + pos / WS) * Ww + wj * WS + pos % WS)) * Cc;
    const long brow = (long)(n0 + sb_row) * Cc;

    const int lane = tid & 63;
    const int wid  = tid >> 6;
    const int wm   = wid >> 1;
    const int wn   = wid & 1;
    const int frow = lane & 15;
    const int kblk = lane >> 4;

    f32x4 acc[4][2];
    #pragma unroll
    for (int i = 0; i < 4; ++i)
        #pragma unroll
        for (int j = 0; j < 2; ++j)
            acc[i][j] = f32x4{0.f, 0.f, 0.f, 0.f};

    for (int k0 = 0; k0 < Cc; k0 += 32) {
        {
            const float* g = x + xrow + k0 + sa_ks;
            float4 f0 = *reinterpret_cast<const float4*>(g);
            float4 f1 = *reinterpret_cast<const float4*>(g + 4);
            float4 f2 = *reinterpret_cast<const float4*>(g + 8);
            float4 f3 = *reinterpret_cast<const float4*>(g + 12);
            bf16x8 p0, p1;
            p0[0]=(__bf16)f0.x; p0[1]=(__bf16)f0.y; p0[2]=(__bf16)f0.z; p0[3]=(__bf16)f0.w;
            p0[4]=(__bf16)f1.x; p0[5]=(__bf16)f1.y; p0[6]=(__bf16)f1.z; p0[7]=(__bf16)f1.w;
            p1[0]=(__bf16)f2.x; p1[1]=(__bf16)f2.y; p1[2]=(__bf16)f2.z; p1[3]=(__bf16)f2.w;
            p1[4]=(__bf16)f3.x; p1[5]=(__bf16)f3.y; p1[6]=(__bf16)f3.z; p1[7]=(__bf16)f3.w;
            *reinterpret_cast<bf16x8*>(&As[sa_row][sa_ks])     = p0;
            *reinterpret_cast<bf16x8*>(&As[sa_row][sa_ks + 8]) = p1;
        }
        {
            const float* g = w + brow + k0 + sb_ks;
            float4 f0 = *reinterpret_cast<const float4*>(g);
            float4 f1 = *reinterpret_cast<const float4*>(g + 4);
            bf16x8 p0;
            p0[0]=(__bf16)f0.x; p0[1]=(__bf16)f0.y; p0[2]=(__bf16)f0.z; p0[3]=(__bf16)f0.w;
            p0[4]=(__bf16)f1.x; p0[5]=(__bf16)f1.y; p0[6]=(__bf16)f1.z; p0[7]=(__bf16)f1.w;
            *reinterpret_cast<bf16x8*>(&Bs[sb_row][sb_ks]) = p0;
        }
        __syncthreads();

        bf16x8 a0 = *reinterpret_cast<const bf16x8*>(&As[wm*64 +  0 + frow][kblk*8]);
        bf16x8 a1 = *reinterpret_cast<const bf16x8*>(&As[wm*64 + 16 + frow][kblk*8]);
        bf16x8 a2 = *reinterpret_cast<const bf16x8*>(&As[wm*64 + 32 + frow][kblk*8]);
        bf16x8 a3 = *reinterpret_cast<const bf16x8*>(&As[wm*64 + 48 + frow][kblk*8]);
        bf16x8 b0 = *reinterpret_cast<const bf16x8*>(&Bs[wn*32 +  0 + frow][kblk*8]);
        bf16x8 b1 = *reinterpret_cast<const bf16x8*>(&Bs[wn*32 + 16 + frow][kblk*8]);

        acc[0][0] = __builtin_amdgcn_mfma_f32_16x16x32_bf16(a0, b0, acc[0][0], 0, 0, 0);
        acc[0][1] = __builtin_amdgcn_mfma_f32_16x16x32_bf16(a0, b1, acc[0][1], 0, 0, 0);
        acc[1][0] = __builtin_amdgcn_mfma_f32_16x16x32_bf16(a1, b0, acc[1][0], 0, 0, 0);
        acc[1][1] = __builtin_amdgcn_mfma_f32_16x16x32_bf16(a1, b1, acc[1][1], 0, 0, 0);
        acc[2][0] = __builtin_amdgcn_mfma_f32_16x16x32_bf16(a2, b0, acc[2][0], 0, 0, 0);
        acc[2][1] = __builtin_amdgcn_mfma_f32_16x16x32_bf16(a2, b1, acc[2][1], 0, 0, 0);
        acc[3][0] = __builtin_amdgcn_mfma_f32_16x16x32_bf16(a3, b0, acc[3][0], 0, 0, 0);
        acc[3][1] = __builtin_amdgcn_mfma_f32_16x16x32_bf16(a3, b1, acc[3][1], 0, 0, 0);
        __syncthreads();
    }

    const int lrow = lane >> 4, lcol = lane & 15;
    #pragma unroll
    for (int fn = 0; fn < 2; ++fn) {
        const int c = n0 + wn*32 + fn*16 + lcol;
        const float bv = bias[c];
        #pragma unroll
        for (int fm = 0; fm < 4; ++fm) {
            const int rbase = m0 + wm*64 + fm*16 + lrow*4;
            #pragma unroll
            for (int r = 0; r < 4; ++r)
                qkv[(long)(rbase + r) * QKVN + c] = f2us(acc[fm][fn][r] + bv);
        }
    }
}

// ---------------------------------------------------------------
// Kernel 2 (MFMA): per-(window, head) attention. (unchanged)
// ---------------------------------------------------------------
__global__ __launch_bounds__(192) void attn_kernel(
        const unsigned short* __restrict__ qkv,    // bf16 [Mrows][576]
        const float* __restrict__ btab,            // f32 [529][8]
        unsigned short* __restrict__ aout)         // bf16 [Mrows][192]
{
    __shared__ unsigned short Klds[WS2][40];
    __shared__ unsigned short Qlds[WS2][40];
    __shared__ unsigned short Vt[32][168];
    __shared__ unsigned short Pl[3][16][168];
    __shared__ float Bh[529];
    __shared__ unsigned short klut[WS2];
    __shared__ float l_inv[3][16];

    const int win  = blockIdx.x;
    const int head = blockIdx.y;
    const int tid  = threadIdx.x;

    const long base = (long)win * WS2 * QKVN;
    const int hoff  = head * HD;

    if (tid < WS2) {
        const uint4* qs = reinterpret_cast<const uint4*>(qkv + base + (long)tid * QKVN + hoff);
        const uint4* ks = reinterpret_cast<const uint4*>(qkv + base + (long)tid * QKVN + Cc + hoff);
        const uint4* vs = reinterpret_cast<const uint4*>(qkv + base + (long)tid * QKVN + 2*Cc + hoff);
        uint4 q0 = qs[0], q1 = qs[1], q2 = qs[2];
        uint4 k0 = ks[0], k1 = ks[1], k2 = ks[2];
        uint4 v0 = vs[0], v1 = vs[1], v2 = vs[2];
        *reinterpret_cast<uint4*>(&Qlds[tid][0])  = q0;
        *reinterpret_cast<uint4*>(&Qlds[tid][8])  = q1;
        *reinterpret_cast<uint4*>(&Qlds[tid][16]) = q2;
        *reinterpret_cast<uint4*>(&Qlds[tid][24]) = uint4{0,0,0,0};
        *reinterpret_cast<uint4*>(&Klds[tid][0])  = k0;
        *reinterpret_cast<uint4*>(&Klds[tid][8])  = k1;
        *reinterpret_cast<uint4*>(&Klds[tid][16]) = k2;
        *reinterpret_cast<uint4*>(&Klds[tid][24]) = uint4{0,0,0,0};
        unsigned short vr[24];
        __builtin_memcpy(&vr[0],  &v0, 16);
        __builtin_memcpy(&vr[8],  &v1, 16);
        __builtin_memcpy(&vr[16], &v2, 16);
        #pragma unroll
        for (int d = 0; d < HD; ++d)
            Vt[d][tid] = vr[d];
    }
    for (int e = tid; e < 8 * 160; e += 192)
        Vt[24 + e / 160][e % 160] = 0;
    for (int e = tid; e < 24 * 16; e += 192)
        Vt[e / 16][144 + (e & 15)] = 0;
    for (int e = tid; e < 529; e += 192)
        Bh[e] = btab[e * HEADS + head];
    if (tid < WS2)
        klut[tid] = (unsigned short)((tid / WS) * 23 + (tid % WS));
    __syncthreads();

    const int wv   = tid >> 6;
    const int lane = tid & 63;
    const int qcol = lane & 15;
    const int g    = lane >> 4;

    #pragma unroll
    for (int i = 0; i < 4; ++i) {
        const int e = lane + i * 64;
        Pl[wv][e >> 4][144 + (e & 15)] = 0;
    }

    const float scale = 0.2041241452319315f;   // 1/sqrt(24)

    #pragma unroll
    for (int ti = 0; ti < 3; ++ti) {
        const int qt = wv * 3 + ti;

        bf16x8 qb = *reinterpret_cast<const bf16x8*>(&Qlds[qt*16 + qcol][g*8]);
        f32x4 s[9];
        #pragma unroll
        for (int t = 0; t < 9; ++t) {
            bf16x8 ka = *reinterpret_cast<const bf16x8*>(&Klds[t*16 + qcol][g*8]);
            s[t] = __builtin_amdgcn_mfma_f32_16x16x32_bf16(ka, qb,
                     f32x4{0.f,0.f,0.f,0.f}, 0, 0, 0);
        }

        const int qpos = qt * 16 + qcol;
        const float bbase = (float)((qpos / WS + 11) * 23 + (qpos % WS + 11));
        float sv[9][4];
        float mx = -1e30f;
        #pragma unroll
        for (int t = 0; t < 9; ++t)
            #pragma unroll
            for (int r = 0; r < 4; ++r) {
                const int kv = t*16 + g*4 + r;
                const int rel = (int)bbase - (int)klut[kv];
                const float v = s[t][r] * scale + Bh[rel];
                sv[t][r] = v;
                mx = fmaxf(mx, v);
            }
        mx = fmaxf(mx, __shfl_xor(mx, 16));
        mx = fmaxf(mx, __shfl_xor(mx, 32));
        float sum = 0.f;
        #pragma unroll
        for (int t = 0; t < 9; ++t)
            #pragma unroll
            for (int r = 0; r < 4; ++r) {
                const float p = __expf(sv[t][r] - mx);
                sv[t][r] = p;
                sum += p;
            }
        sum += __shfl_xor(sum, 16);
        sum += __shfl_xor(sum, 32);
        if (g == 0)
            l_inv[wv][qcol] = 1.f / sum;

        #pragma unroll
        for (int t = 0; t < 9; ++t)
            #pragma unroll
            for (int r = 0; r < 4; ++r)
                Pl[wv][qcol][t*16 + g*4 + r] = f2us(sv[t][r]);

        f32x4 o0 = {0.f,0.f,0.f,0.f}, o1 = {0.f,0.f,0.f,0.f};
        #pragma unroll
        for (int ks = 0; ks < 5; ++ks) {
            bf16x8 pa  = *reinterpret_cast<const bf16x8*>(&Pl[wv][qcol][ks*32 + g*8]);
            bf16x8 vb0 = *reinterpret_cast<const bf16x8*>(&Vt[qcol     ][ks*32 + g*8]);
            bf16x8 vb1 = *reinterpret_cast<const bf16x8*>(&Vt[16 + qcol][ks*32 + g*8]);
            o0 = __builtin_amdgcn_mfma_f32_16x16x32_bf16(pa, vb0, o0, 0, 0, 0);
            o1 = __builtin_amdgcn_mfma_f32_16x16x32_bf16(pa, vb1, o1, 0, 0, 0);
        }

        #pragma unroll
        for (int idx = 0; idx < 4; ++idx) {
            const int qrow = qt*16 + g*4 + idx;
            const float li = l_inv[wv][g*4 + idx];
            const long ob = (long)(win * WS2 + qrow) * Cc + hoff;
            aout[ob + qcol] = f2us(o0[idx] * li);
            if (qcol < 8)
                aout[ob + 16 + qcol] = f2us(o1[idx] * li);
        }
    }
}

// ---------------------------------------------------------------
// Kernel 3 (MFMA): out = window_reverse(aout @ proj_w^T + proj_b)
// Pure GEMM + scatter write; LPE moved to its own kernel.
// ---------------------------------------------------------------
__global__ __launch_bounds__(256) void proj_gemm(
        const unsigned short* __restrict__ aout,   // bf16 [Mrows][192]
        const float* __restrict__ pw,              // f32 [192][192]
        const float* __restrict__ pb,              // f32 [192]
        float* __restrict__ out)                   // f32 [B*N*C]
{
    __shared__ __bf16 As[128][LDP];
    __shared__ __bf16 Bs[64][LDP];

    const int tid = threadIdx.x;
    const int m0  = blockIdx.x * 128;
    const int n0  = blockIdx.y * 64;

    const int sa_row = tid >> 1;
    const int sa_ks  = (tid & 1) * 16;
    const int sb_row = tid >> 2;
    const int sb_ks  = (tid & 3) * 8;

    const long arow = (long)(m0 + sa_row) * Cc;
    const long brow = (long)(n0 + sb_row) * Cc;

    const int lane = tid & 63;
    const int wid  = tid >> 6;
    const int wm   = wid >> 1;
    const int wn   = wid & 1;
    const int frow = lane & 15;
    const int kblk = lane >> 4;

    f32x4 acc[4][2];
    #pragma unroll
    for (int i = 0; i < 4; ++i)
        #pragma unroll
        for (int j = 0; j < 2; ++j)
            acc[i][j] = f32x4{0.f, 0.f, 0.f, 0.f};

    for (int k0 = 0; k0 < Cc; k0 += 32) {
        {
            const unsigned short* g = aout + arow + k0 + sa_ks;
            uint4 v0 = *reinterpret_cast<const uint4*>(g);
            uint4 v1 = *reinterpret_cast<const uint4*>(g + 8);
            *reinterpret_cast<uint4*>(&As[sa_row][sa_ks])     = v0;
            *reinterpret_cast<uint4*>(&As[sa_row][sa_ks + 8]) = v1;
        }
        {
            const float* g = pw + brow + k0 + sb_ks;
            float4 f0 = *reinterpret_cast<const float4*>(g);
            float4 f1 = *reinterpret_cast<const float4*>(g + 4);
            bf16x8 p0;
            p0[0]=(__bf16)f0.x; p0[1]=(__bf16)f0.y; p0[2]=(__bf16)f0.z; p0[3]=(__bf16)f0.w;
            p0[4]=(__bf16)f1.x; p0[5]=(__bf16)f1.y; p0[6]=(__bf16)f1.z; p0[7]=(__bf16)f1.w;
            *reinterpret_cast<bf16x8*>(&Bs[sb_row][sb_ks]) = p0;
        }
        __syncthreads();

        bf16x8 a0 = *reinterpret_cast<const bf16x8*>(&As[wm*64 +  0 + frow][kblk*8]);
        bf16x8 a1 = *reinterpret_cast<const bf16x8*>(&As[wm*64 + 16 + frow][kblk*8]);
        bf16x8 a2 = *reinterpret_cast<const bf16x8*>(&As[wm*64 + 32 + frow][kblk*8]);
        bf16x8 a3 = *reinterpret_cast<const bf16x8*>(&As[wm*64 + 48 + frow][kblk*8]);
        bf16x8 b0 = *reinterpret_cast<const bf16x8*>(&Bs[wn*32 +  0 + frow][kblk*8]);
        bf16x8 b1 = *reinterpret_cast<const bf16x8*>(&Bs[wn*32 + 16 + frow][kblk*8]);

        acc[0][0] = __builtin_amdgcn_mfma_f32_16x16x32_bf16(a0, b0, acc[0][0], 0, 0, 0);
        acc[0][1] = __builtin_amdgcn_mfma_f32_16x16x32_bf16(a0, b1, acc[0][1], 0, 0, 0);
        acc[1][0] = __builtin_amdgcn_mfma_f32_16x16x32_bf16(a1, b0, acc[1][0], 0, 0, 0);
        acc[1][1] = __builtin_amdgcn_mfma_f32_16x16x32_bf16(a1, b1, acc[1][1], 0, 0, 0);
        acc[2][0] = __builtin_amdgcn_mfma_f32_16x16x32_bf16(a2, b0, acc[2][0], 0, 0, 0);
        acc[2][1] = __builtin_amdgcn_mfma_f32_16x16x32_bf16(a2, b1, acc[2][1], 0, 0, 0);
        acc[3][0] = __builtin_amdgcn_mfma_f32_16x16x32_bf16(a3, b0, acc[3][0], 0, 0, 0);
        acc[3][1] = __builtin_amdgcn_mfma_f32_16x16x32_bf16(a3, b1, acc[3][1], 0, 0, 0);
        __syncthreads();
    }

    const int lrow = lane >> 4, lcol = lane & 15;

    #pragma unroll
    for (int fm = 0; fm < 4; ++fm) {
        #pragma unroll
        for (int r = 0; r < 4; ++r) {
            const int mrow = m0 + wm*64 + fm*16 + lrow*4 + r;
            const int widx = mrow / WS2;
            const int pos  = mrow % WS2;
            const int b    = widx >> 6;
            const int wi   = (widx >> 3) & 7;
            const int wj   = widx & 7;
            const int h    = wi * WS + pos / WS;
            const int w_   = wj * WS + pos % WS;
            const long orow = ((long)(b * Hh + h) * Ww + w_) * Cc;

            #pragma unroll
            for (int fn = 0; fn < 2; ++fn) {
                const int c = n0 + wn*32 + fn*16 + lcol;
                out[orow + c] = acc[fm][fn][r] + pb[c];
            }
        }
    }
}

// ---------------------------------------------------------------
// Kernel 4: out += (depthwise3x3(x) + lb) * lsc * mask
// Thread = (pixel, 4 channels). NHWC float4 vectorized, weights
// transposed [tap][c] in LDS for b128 conflict-free reads.
// ---------------------------------------------------------------
__global__ __launch_bounds__(256) void lpe_add(
        const float* __restrict__ x,               // f32 [B*H*W*C]
        const float* __restrict__ lw,              // f32 [192][9]
        const float* __restrict__ lb,              // f32 [192]
        const float* __restrict__ lsc,             // f32 [1]
        const float* __restrict__ mask,            // f32 [B*H*W]
        float* __restrict__ out)                   // f32 [B*H*W*C]
{
    __shared__ float lwt[9][Cc];
    __shared__ float lbs[Cc];

    const int tid = threadIdx.x;
    for (int e = tid; e < Cc * 9; e += 256) {
        const int c = e / 9, tap = e % 9;
        lwt[tap][c] = lw[e];
    }
    for (int e = tid; e < Cc; e += 256)
        lbs[e] = lb[e];
    __syncthreads();

    const float ls = lsc[0];
    const long idx = (long)blockIdx.x * 256 + tid;   // 0 .. 73728*48-1
    const int c  = ((int)(idx % 48)) * 4;
    const int p  = (int)(idx / 48);                  // pixel (b*H+h)*W+w
    const int w_ = p % Ww;
    const int h  = (p / Ww) % Hh;

    float4 acc = *reinterpret_cast<const float4*>(&lbs[c]);
    #pragma unroll
    for (int kh = -1; kh <= 1; ++kh) {
        const int hh = h + kh;
        if (hh < 0 || hh >= Hh) continue;
        #pragma unroll
        for (int kw = -1; kw <= 1; ++kw) {
            const int ww = w_ + kw;
            if (ww < 0 || ww >= Ww) continue;
            const float4 xv = *reinterpret_cast<const float4*>(
                x + ((long)p + kh * Ww + kw) * Cc + c);
            const float4 wv = *reinterpret_cast<const float4*>(&lwt[(kh+1)*3 + (kw+1)][c]);
            acc.x += xv.x * wv.x;
            acc.y += xv.y * wv.y;
            acc.z += xv.z * wv.z;
            acc.w += xv.w * wv.w;
        }
    }
    const float mv = mask[p] * ls;
    float* op = out + (long)p * Cc + c;
    float4 o = *reinterpret_cast<const float4*>(op);
    o.x += acc.x * mv;
    o.y += acc.y * mv;
    o.z += acc.z * mv;
    o.w += acc.w * mv;
    *reinterpret_cast<float4*>(op) = o;
}

// ---------------------------------------------------------------
extern "C" void kernel_launch(void* const* d_in, const int* in_sizes, int n_in,
                              void* d_out, int out_size, void* d_ws, size_t ws_size,
                              hipStream_t stream) {
    const float* x    = (const float*)d_in[0];
    const float* mask = (const float*)d_in[1];
    const float* qw   = (const float*)d_in[2];
    const float* qb   = (const float*)d_in[3];
    const float* pw   = (const float*)d_in[4];
    const float* pb   = (const float*)d_in[5];
    const float* lw   = (const float*)d_in[6];
    const float* lb   = (const float*)d_in[7];
    const float* lsc  = (const float*)d_in[8];
    const float* btab = (const float*)d_in[9];

    unsigned short* qkv  = (unsigned short*)d_ws;                // bf16 [73728][576]
    unsigned short* aout = qkv + (size_t)Mrows * QKVN;           // bf16 [73728][192]

    qkv_gemm<<<dim3(Mrows/128, QKVN/64), dim3(256), 0, stream>>>(x, qw, qb, qkv);
    attn_kernel<<<dim3(NWIN, HEADS), dim3(192), 0, stream>>>(qkv, btab, aout);
    proj_gemm<<<dim3(Mrows/128, Cc/64), dim3(256), 0, stream>>>(aout, pw, pb, (float*)d_out);
    lpe_add<<<dim3((Mrows * 48) / 256), dim3(256), 0, stream>>>(x, lw, lb, lsc, mask,
                                                                (float*)d_out);
}

// Round 7
// 336.778 us; speedup vs baseline: 2.7512x; 1.0111x over previous
//
#include <hip/hip_runtime.h>
#include <hip/hip_bf16.h>

// ---------- constants ----------
constexpr int Bb   = 8;
constexpr int Hh   = 96;
constexpr int Ww   = 96;
constexpr int Cc   = 192;
constexpr int WS   = 12;
constexpr int WS2  = 144;            // 12*12
constexpr int HEADS= 8;
constexpr int HD   = 24;
constexpr int NWIN = Bb * (Hh/WS) * (Ww/WS);   // 512
constexpr int Mrows= NWIN * WS2;               // 73728
constexpr int QKVN = 3 * Cc;                   // 576

typedef __bf16 bf16x8 __attribute__((ext_vector_type(8)));
typedef float  f32x4  __attribute__((ext_vector_type(4)));

constexpr int LDP  = 40;   // GEMM LDS row stride (bf16)
constexpr int APAD = 170;  // attn LDS row stride: 340B = 85 dwords (odd) -> banks spread

__device__ __forceinline__ float us2f(unsigned short u) {
    unsigned int i = ((unsigned int)u) << 16;
    float f; __builtin_memcpy(&f, &i, 4);
    return f;
}
__device__ __forceinline__ unsigned short f2us(float f) {
    unsigned int i; __builtin_memcpy(&i, &f, 4);
    unsigned int lsb = (i >> 16) & 1u;
    i += 0x7fffu + lsb;
    return (unsigned short)(i >> 16);
}

// ---------------------------------------------------------------
// Kernel 1 (MFMA): qkv = window_partition(x) @ qkv_w^T + qkv_b
// grid: (bn fastest) so 9 consecutive blocks share one A-tile (L2 reuse)
// ---------------------------------------------------------------
__global__ __launch_bounds__(256) void qkv_gemm(
        const float* __restrict__ x,      // f32 [B*N*C]
        const float* __restrict__ w,      // f32 [576][192]
        const float* __restrict__ bias,   // f32 [576]
        unsigned short* __restrict__ qkv) // bf16 [Mrows][576]
{
    __shared__ __bf16 As[128][LDP];
    __shared__ __bf16 Bs[64][LDP];

    const int tid = threadIdx.x;
    const int n0  = blockIdx.x * 64;
    const int m0  = blockIdx.y * 128;

    const int sa_row = tid >> 1;
    const int sa_ks  = (tid & 1) * 16;
    const int sb_row = tid >> 2;
    const int sb_ks  = (tid & 3) * 8;

    const int m    = m0 + sa_row;
    const int widx = m / WS2;
    const int pos  = m % WS2;
    const int b    = widx >> 6;
    const int wi   = (widx >> 3) & 7;
    const int wj   = widx & 7;
    const long xrow = ((long)((b * Hh + wi * WS + pos / WS) * Ww + wj * WS + pos % WS)) * Cc;
    const long brow = (long)(n0 + sb_row) * Cc;

    const int lane = tid & 63;
    const int wid  = tid >> 6;
    const int wm   = wid >> 1;
    const int wn   = wid & 1;
    const int frow = lane & 15;
    const int kblk = lane >> 4;

    f32x4 acc[4][2];
    #pragma unroll
    for (int i = 0; i < 4; ++i)
        #pragma unroll
        for (int j = 0; j < 2; ++j)
            acc[i][j] = f32x4{0.f, 0.f, 0.f, 0.f};

    for (int k0 = 0; k0 < Cc; k0 += 32) {
        {
            const float* g = x + xrow + k0 + sa_ks;
            float4 f0 = *reinterpret_cast<const float4*>(g);
            float4 f1 = *reinterpret_cast<const float4*>(g + 4);
            float4 f2 = *reinterpret_cast<const float4*>(g + 8);
            float4 f3 = *reinterpret_cast<const float4*>(g + 12);
            bf16x8 p0, p1;
            p0[0]=(__bf16)f0.x; p0[1]=(__bf16)f0.y; p0[2]=(__bf16)f0.z; p0[3]=(__bf16)f0.w;
            p0[4]=(__bf16)f1.x; p0[5]=(__bf16)f1.y; p0[6]=(__bf16)f1.z; p0[7]=(__bf16)f1.w;
            p1[0]=(__bf16)f2.x; p1[1]=(__bf16)f2.y; p1[2]=(__bf16)f2.z; p1[3]=(__bf16)f2.w;
            p1[4]=(__bf16)f3.x; p1[5]=(__bf16)f3.y; p1[6]=(__bf16)f3.z; p1[7]=(__bf16)f3.w;
            *reinterpret_cast<bf16x8*>(&As[sa_row][sa_ks])     = p0;
            *reinterpret_cast<bf16x8*>(&As[sa_row][sa_ks + 8]) = p1;
        }
        {
            const float* g = w + brow + k0 + sb_ks;
            float4 f0 = *reinterpret_cast<const float4*>(g);
            float4 f1 = *reinterpret_cast<const float4*>(g + 4);
            bf16x8 p0;
            p0[0]=(__bf16)f0.x; p0[1]=(__bf16)f0.y; p0[2]=(__bf16)f0.z; p0[3]=(__bf16)f0.w;
            p0[4]=(__bf16)f1.x; p0[5]=(__bf16)f1.y; p0[6]=(__bf16)f1.z; p0[7]=(__bf16)f1.w;
            *reinterpret_cast<bf16x8*>(&Bs[sb_row][sb_ks]) = p0;
        }
        __syncthreads();

        bf16x8 a0 = *reinterpret_cast<const bf16x8*>(&As[wm*64 +  0 + frow][kblk*8]);
        bf16x8 a1 = *reinterpret_cast<const bf16x8*>(&As[wm*64 + 16 + frow][kblk*8]);
        bf16x8 a2 = *reinterpret_cast<const bf16x8*>(&As[wm*64 + 32 + frow][kblk*8]);
        bf16x8 a3 = *reinterpret_cast<const bf16x8*>(&As[wm*64 + 48 + frow][kblk*8]);
        bf16x8 b0 = *reinterpret_cast<const bf16x8*>(&Bs[wn*32 +  0 + frow][kblk*8]);
        bf16x8 b1 = *reinterpret_cast<const bf16x8*>(&Bs[wn*32 + 16 + frow][kblk*8]);

        acc[0][0] = __builtin_amdgcn_mfma_f32_16x16x32_bf16(a0, b0, acc[0][0], 0, 0, 0);
        acc[0][1] = __builtin_amdgcn_mfma_f32_16x16x32_bf16(a0, b1, acc[0][1], 0, 0, 0);
        acc[1][0] = __builtin_amdgcn_mfma_f32_16x16x32_bf16(a1, b0, acc[1][0], 0, 0, 0);
        acc[1][1] = __builtin_amdgcn_mfma_f32_16x16x32_bf16(a1, b1, acc[1][1], 0, 0, 0);
        acc[2][0] = __builtin_amdgcn_mfma_f32_16x16x32_bf16(a2, b0, acc[2][0], 0, 0, 0);
        acc[2][1] = __builtin_amdgcn_mfma_f32_16x16x32_bf16(a2, b1, acc[2][1], 0, 0, 0);
        acc[3][0] = __builtin_amdgcn_mfma_f32_16x16x32_bf16(a3, b0, acc[3][0], 0, 0, 0);
        acc[3][1] = __builtin_amdgcn_mfma_f32_16x16x32_bf16(a3, b1, acc[3][1], 0, 0, 0);
        __syncthreads();
    }

    const int lrow = lane >> 4, lcol = lane & 15;
    #pragma unroll
    for (int fn = 0; fn < 2; ++fn) {
        const int c = n0 + wn*32 + fn*16 + lcol;
        const float bv = bias[c];
        #pragma unroll
        for (int fm = 0; fm < 4; ++fm) {
            const int rbase = m0 + wm*64 + fm*16 + lrow*4;
            #pragma unroll
            for (int r = 0; r < 4; ++r)
                qkv[(long)(rbase + r) * QKVN + c] = f2us(acc[fm][fn][r] + bv);
        }
    }
}

// ---------------------------------------------------------------
// Kernel 2 (MFMA) v2: per-(window, head) attention.
// K fragments preloaded to registers (q-tile invariant), Q fragments
// loaded direct from global; only V^T, P, bias in LDS (~30 KB ->
// 5 blocks/CU). d-pad 24->32 realized as zeroed g==3 fragments.
// ---------------------------------------------------------------
__global__ __launch_bounds__(192, 4) void attn_kernel(
        const unsigned short* __restrict__ qkv,    // bf16 [Mrows][576]
        const float* __restrict__ btab,            // f32 [529][8]
        unsigned short* __restrict__ aout)         // bf16 [Mrows][192]
{
    __shared__ unsigned short Vt[32][APAD];      // [d][kv]
    __shared__ unsigned short Pl[3][16][APAD];   // per-wave P slab [q][kv]
    __shared__ float Bh[529];
    __shared__ unsigned short klut[WS2];
    __shared__ float l_inv[3][16];

    const int head = blockIdx.x;     // fastest -> blocks sharing a window adjacent
    const int win  = blockIdx.y;
    const int tid  = threadIdx.x;

    const long base = (long)win * WS2 * QKVN;
    const int hoff  = head * HD;

    // ---- V staging (transpose to [d][kv]) ----
    if (tid < WS2) {
        const uint4* vs = reinterpret_cast<const uint4*>(qkv + base + (long)tid * QKVN + 2*Cc + hoff);
        uint4 v0 = vs[0], v1 = vs[1], v2 = vs[2];
        unsigned short vr[24];
        __builtin_memcpy(&vr[0],  &v0, 16);
        __builtin_memcpy(&vr[8],  &v1, 16);
        __builtin_memcpy(&vr[16], &v2, 16);
        #pragma unroll
        for (int d = 0; d < HD; ++d)
            Vt[d][tid] = vr[d];
    }
    for (int e = tid; e < 8 * 160; e += 192)
        Vt[24 + e / 160][e % 160] = 0;
    for (int e = tid; e < 24 * 16; e += 192)
        Vt[e / 16][144 + (e & 15)] = 0;
    for (int e = tid; e < 529; e += 192)
        Bh[e] = btab[e * HEADS + head];
    if (tid < WS2)
        klut[tid] = (unsigned short)((tid / WS) * 23 + (tid % WS));

    const int wv   = tid >> 6;
    const int lane = tid & 63;
    const int qcol = lane & 15;
    const int g    = lane >> 4;

    bf16x8 zerov;
    #pragma unroll
    for (int i = 0; i < 8; ++i) zerov[i] = (__bf16)0.0f;

    // ---- K fragments: register-resident, q-tile invariant ----
    bf16x8 ka[9];
    if (g < 3) {
        #pragma unroll
        for (int t = 0; t < 9; ++t)
            ka[t] = *reinterpret_cast<const bf16x8*>(
                qkv + base + (long)(t*16 + qcol) * QKVN + Cc + hoff + g*8);
    } else {
        #pragma unroll
        for (int t = 0; t < 9; ++t) ka[t] = zerov;
    }

    // zero P pad cols 144..159 (wave-private slab)
    #pragma unroll
    for (int i = 0; i < 4; ++i) {
        const int e = lane + i * 64;
        Pl[wv][e >> 4][144 + (e & 15)] = 0;
    }
    __syncthreads();

    const float scale = 0.2041241452319315f;   // 1/sqrt(24)

    #pragma unroll
    for (int ti = 0; ti < 3; ++ti) {
        const int qt = wv * 3 + ti;

        // ---- QK^T: S^T tiles; Q fragment direct from global ----
        bf16x8 qb = zerov;
        if (g < 3)
            qb = *reinterpret_cast<const bf16x8*>(
                qkv + base + (long)(qt*16 + qcol) * QKVN + hoff + g*8);

        f32x4 s[9];
        #pragma unroll
        for (int t = 0; t < 9; ++t)
            s[t] = __builtin_amdgcn_mfma_f32_16x16x32_bf16(ka[t], qb,
                     f32x4{0.f,0.f,0.f,0.f}, 0, 0, 0);
        // lane holds: q = qcol, kv = t*16 + g*4 + r

        // ---- softmax (row spread over lanes qcol, +16, +32, +48) ----
        const int qpos = qt * 16 + qcol;
        const float bbase = (float)((qpos / WS + 11) * 23 + (qpos % WS + 11));
        float sv[9][4];
        float mx = -1e30f;
        #pragma unroll
        for (int t = 0; t < 9; ++t)
            #pragma unroll
            for (int r = 0; r < 4; ++r) {
                const int kv = t*16 + g*4 + r;
                const int rel = (int)bbase - (int)klut[kv];
                const float v = s[t][r] * scale + Bh[rel];
                sv[t][r] = v;
                mx = fmaxf(mx, v);
            }
        mx = fmaxf(mx, __shfl_xor(mx, 16));
        mx = fmaxf(mx, __shfl_xor(mx, 32));
        float sum = 0.f;
        #pragma unroll
        for (int t = 0; t < 9; ++t)
            #pragma unroll
            for (int r = 0; r < 4; ++r) {
                const float p = __expf(sv[t][r] - mx);
                sv[t][r] = p;
                sum += p;
            }
        sum += __shfl_xor(sum, 16);
        sum += __shfl_xor(sum, 32);
        if (g == 0)
            l_inv[wv][qcol] = 1.f / sum;

        // ---- P -> wave-private LDS (bf16) ----
        #pragma unroll
        for (int t = 0; t < 9; ++t)
            #pragma unroll
            for (int r = 0; r < 4; ++r)
                Pl[wv][qcol][t*16 + g*4 + r] = f2us(sv[t][r]);

        // ---- PV: O[q][d], 5 K-steps x 2 d-tiles ----
        f32x4 o0 = {0.f,0.f,0.f,0.f}, o1 = {0.f,0.f,0.f,0.f};
        #pragma unroll
        for (int ks = 0; ks < 5; ++ks) {
            bf16x8 pa  = *reinterpret_cast<const bf16x8*>(&Pl[wv][qcol][ks*32 + g*8]);
            bf16x8 vb0 = *reinterpret_cast<const bf16x8*>(&Vt[qcol     ][ks*32 + g*8]);
            bf16x8 vb1 = *reinterpret_cast<const bf16x8*>(&Vt[16 + qcol][ks*32 + g*8]);
            o0 = __builtin_amdgcn_mfma_f32_16x16x32_bf16(pa, vb0, o0, 0, 0, 0);
            o1 = __builtin_amdgcn_mfma_f32_16x16x32_bf16(pa, vb1, o1, 0, 0, 0);
        }

        // ---- epilogue ----
        #pragma unroll
        for (int idx = 0; idx < 4; ++idx) {
            const int qrow = qt*16 + g*4 + idx;
            const float li = l_inv[wv][g*4 + idx];
            const long ob = (long)(win * WS2 + qrow) * Cc + hoff;
            aout[ob + qcol] = f2us(o0[idx] * li);
            if (qcol < 8)
                aout[ob + 16 + qcol] = f2us(o1[idx] * li);
        }
    }
}

// ---------------------------------------------------------------
// Kernel 3 (MFMA): out = window_reverse(aout @ proj_w^T + proj_b)
// ---------------------------------------------------------------
__global__ __launch_bounds__(256) void proj_gemm(
        const unsigned short* __restrict__ aout,   // bf16 [Mrows][192]
        const float* __restrict__ pw,              // f32 [192][192]
        const float* __restrict__ pb,              // f32 [192]
        float* __restrict__ out)                   // f32 [B*N*C]
{
    __shared__ __bf16 As[128][LDP];
    __shared__ __bf16 Bs[64][LDP];

    const int tid = threadIdx.x;
    const int n0  = blockIdx.x * 64;
    const int m0  = blockIdx.y * 128;

    const int sa_row = tid >> 1;
    const int sa_ks  = (tid & 1) * 16;
    const int sb_row = tid >> 2;
    const int sb_ks  = (tid & 3) * 8;

    const long arow = (long)(m0 + sa_row) * Cc;
    const long brow = (long)(n0 + sb_row) * Cc;

    const int lane = tid & 63;
    const int wid  = tid >> 6;
    const int wm   = wid >> 1;
    const int wn   = wid & 1;
    const int frow = lane & 15;
    const int kblk = lane >> 4;

    f32x4 acc[4][2];
    #pragma unroll
    for (int i = 0; i < 4; ++i)
        #pragma unroll
        for (int j = 0; j < 2; ++j)
            acc[i][j] = f32x4{0.f, 0.f, 0.f, 0.f};

    for (int k0 = 0; k0 < Cc; k0 += 32) {
        {
            const unsigned short* g = aout + arow + k0 + sa_ks;
            uint4 v0 = *reinterpret_cast<const uint4*>(g);
            uint4 v1 = *reinterpret_cast<const uint4*>(g + 8);
            *reinterpret_cast<uint4*>(&As[sa_row][sa_ks])     = v0;
            *reinterpret_cast<uint4*>(&As[sa_row][sa_ks + 8]) = v1;
        }
        {
            const float* g = pw + brow + k0 + sb_ks;
            float4 f0 = *reinterpret_cast<const float4*>(g);
            float4 f1 = *reinterpret_cast<const float4*>(g + 4);
            bf16x8 p0;
            p0[0]=(__bf16)f0.x; p0[1]=(__bf16)f0.y; p0[2]=(__bf16)f0.z; p0[3]=(__bf16)f0.w;
            p0[4]=(__bf16)f1.x; p0[5]=(__bf16)f1.y; p0[6]=(__bf16)f1.z; p0[7]=(__bf16)f1.w;
            *reinterpret_cast<bf16x8*>(&Bs[sb_row][sb_ks]) = p0;
        }
        __syncthreads();

        bf16x8 a0 = *reinterpret_cast<const bf16x8*>(&As[wm*64 +  0 + frow][kblk*8]);
        bf16x8 a1 = *reinterpret_cast<const bf16x8*>(&As[wm*64 + 16 + frow][kblk*8]);
        bf16x8 a2 = *reinterpret_cast<const bf16x8*>(&As[wm*64 + 32 + frow][kblk*8]);
        bf16x8 a3 = *reinterpret_cast<const bf16x8*>(&As[wm*64 + 48 + frow][kblk*8]);
        bf16x8 b0 = *reinterpret_cast<const bf16x8*>(&Bs[wn*32 +  0 + frow][kblk*8]);
        bf16x8 b1 = *reinterpret_cast<const bf16x8*>(&Bs[wn*32 + 16 + frow][kblk*8]);

        acc[0][0] = __builtin_amdgcn_mfma_f32_16x16x32_bf16(a0, b0, acc[0][0], 0, 0, 0);
        acc[0][1] = __builtin_amdgcn_mfma_f32_16x16x32_bf16(a0, b1, acc[0][1], 0, 0, 0);
        acc[1][0] = __builtin_amdgcn_mfma_f32_16x16x32_bf16(a1, b0, acc[1][0], 0, 0, 0);
        acc[1][1] = __builtin_amdgcn_mfma_f32_16x16x32_bf16(a1, b1, acc[1][1], 0, 0, 0);
        acc[2][0] = __builtin_amdgcn_mfma_f32_16x16x32_bf16(a2, b0, acc[2][0], 0, 0, 0);
        acc[2][1] = __builtin_amdgcn_mfma_f32_16x16x32_bf16(a2, b1, acc[2][1], 0, 0, 0);
        acc[3][0] = __builtin_amdgcn_mfma_f32_16x16x32_bf16(a3, b0, acc[3][0], 0, 0, 0);
        acc[3][1] = __builtin_amdgcn_mfma_f32_16x16x32_bf16(a3, b1, acc[3][1], 0, 0, 0);
        __syncthreads();
    }

    const int lrow = lane >> 4, lcol = lane & 15;

    #pragma unroll
    for (int fm = 0; fm < 4; ++fm) {
        #pragma unroll
        for (int r = 0; r < 4; ++r) {
            const int mrow = m0 + wm*64 + fm*16 + lrow*4 + r;
            const int widx = mrow / WS2;
            const int pos  = mrow % WS2;
            const int b    = widx >> 6;
            const int wi   = (widx >> 3) & 7;
            const int wj   = widx & 7;
            const int h    = wi * WS + pos / WS;
            const int w_   = wj * WS + pos % WS;
            const long orow = ((long)(b * Hh + h) * Ww + w_) * Cc;

            #pragma unroll
            for (int fn = 0; fn < 2; ++fn) {
                const int c = n0 + wn*32 + fn*16 + lcol;
                out[orow + c] = acc[fm][fn][r] + pb[c];
            }
        }
    }
}

// ---------------------------------------------------------------
// Kernel 4: out += (depthwise3x3(x) + lb) * lsc * mask
// ---------------------------------------------------------------
__global__ __launch_bounds__(256) void lpe_add(
        const float* __restrict__ x,               // f32 [B*H*W*C]
        const float* __restrict__ lw,              // f32 [192][9]
        const float* __restrict__ lb,              // f32 [192]
        const float* __restrict__ lsc,             // f32 [1]
        const float* __restrict__ mask,            // f32 [B*H*W]
        float* __restrict__ out)                   // f32 [B*H*W*C]
{
    __shared__ float lwt[9][Cc];
    __shared__ float lbs[Cc];

    const int tid = threadIdx.x;
    for (int e = tid; e < Cc * 9; e += 256) {
        const int c = e / 9, tap = e % 9;
        lwt[tap][c] = lw[e];
    }
    for (int e = tid; e < Cc; e += 256)
        lbs[e] = lb[e];
    __syncthreads();

    const float ls = lsc[0];
    const long idx = (long)blockIdx.x * 256 + tid;
    const int c  = ((int)(idx % 48)) * 4;
    const int p  = (int)(idx / 48);
    const int w_ = p % Ww;
    const int h  = (p / Ww) % Hh;

    float4 acc = *reinterpret_cast<const float4*>(&lbs[c]);
    #pragma unroll
    for (int kh = -1; kh <= 1; ++kh) {
        const int hh = h + kh;
        if (hh < 0 || hh >= Hh) continue;
        #pragma unroll
        for (int kw = -1; kw <= 1; ++kw) {
            const int ww = w_ + kw;
            if (ww < 0 || ww >= Ww) continue;
            const float4 xv = *reinterpret_cast<const float4*>(
                x + ((long)p + kh * Ww + kw) * Cc + c);
            const float4 wv = *reinterpret_cast<const float4*>(&lwt[(kh+1)*3 + (kw+1)][c]);
            acc.x += xv.x * wv.x;
            acc.y += xv.y * wv.y;
            acc.z += xv.z * wv.z;
            acc.w += xv.w * wv.w;
        }
    }
    const float mv = mask[p] * ls;
    float* op = out + (long)p * Cc + c;
    float4 o = *reinterpret_cast<const float4*>(op);
    o.x += acc.x * mv;
    o.y += acc.y * mv;
    o.z += acc.z * mv;
    o.w += acc.w * mv;
    *reinterpret_cast<float4*>(op) = o;
}

// ---------------------------------------------------------------
extern "C" void kernel_launch(void* const* d_in, const int* in_sizes, int n_in,
                              void* d_out, int out_size, void* d_ws, size_t ws_size,
                              hipStream_t stream) {
    const float* x    = (const float*)d_in[0];
    const float* mask = (const float*)d_in[1];
    const float* qw   = (const float*)d_in[2];
    const float* qb   = (const float*)d_in[3];
    const float* pw   = (const float*)d_in[4];
    const float* pb   = (const float*)d_in[5];
    const float* lw   = (const float*)d_in[6];
    const float* lb   = (const float*)d_in[7];
    const float* lsc  = (const float*)d_in[8];
    const float* btab = (const float*)d_in[9];

    unsigned short* qkv  = (unsigned short*)d_ws;                // bf16 [73728][576]
    unsigned short* aout = qkv + (size_t)Mrows * QKVN;           // bf16 [73728][192]

    qkv_gemm<<<dim3(QKVN/64, Mrows/128), dim3(256), 0, stream>>>(x, qw, qb, qkv);
    attn_kernel<<<dim3(HEADS, NWIN), dim3(192), 0, stream>>>(qkv, btab, aout);
    proj_gemm<<<dim3(Cc/64, Mrows/128), dim3(256), 0, stream>>>(aout, pw, pb, (float*)d_out);
    lpe_add<<<dim3((Mrows * 48) / 256), dim3(256), 0, stream>>>(x, lw, lb, lsc, mask,
                                                                (float*)d_out);
}